// Round 8
// baseline (471.608 us; speedup 1.0000x reference)
//
#include <hip/hip_runtime.h>
#include <hip/hip_bf16.h>
#include <math.h>

typedef __bf16 bf16_t;
typedef __bf16 bf16x4 __attribute__((ext_vector_type(4)));
typedef short  s16x8  __attribute__((ext_vector_type(8)));
typedef float  f32x4  __attribute__((ext_vector_type(4)));

#define DEVINL __device__ __forceinline__

DEVINL void gload_lds16(const void* g, void* l) {
  __builtin_amdgcn_global_load_lds(
      (const __attribute__((address_space(1))) unsigned int*)g,
      (__attribute__((address_space(3))) unsigned int*)l, 16, 0, 0);
}

DEVINL f32x4 mfma16(s16x8 a, s16x8 b, f32x4 c) {
  return __builtin_amdgcn_mfma_f32_16x16x32_bf16(a, b, c, 0, 0, 0);
}

// ---------------- transpose + cast: W[K][N] f32 -> WT[N][K] bf16 ----------------
__global__ __launch_bounds__(256) void tcast_kernel(const float* __restrict__ W,
                                                    bf16_t* __restrict__ WT,
                                                    int K, int N) {
  __shared__ float tile[32][33];
  const int n0 = blockIdx.x * 32, k0 = blockIdx.y * 32;
  const int tx = threadIdx.x, ty = threadIdx.y;
#pragma unroll
  for (int j = 0; j < 4; ++j)
    tile[ty + j * 8][tx] = W[(size_t)(k0 + ty + j * 8) * N + (n0 + tx)];
  __syncthreads();
#pragma unroll
  for (int j = 0; j < 4; ++j)
    WT[(size_t)(n0 + ty + j * 8) * K + (k0 + tx)] = (bf16_t)tile[tx][ty + j * 8];
}

// ---------------- layernorm: f32 [rows][1024] -> bf16 ----------------
__global__ __launch_bounds__(256) void ln_kernel(const float* __restrict__ x,
                                                 const float* __restrict__ w,
                                                 const float* __restrict__ b,
                                                 bf16_t* __restrict__ out) {
  const int row = blockIdx.x, tid = threadIdx.x;
  const float4 v = ((const float4*)(x + (size_t)row * 1024))[tid];
  float s  = v.x + v.y + v.z + v.w;
  float s2 = v.x * v.x + v.y * v.y + v.z * v.z + v.w * v.w;
#pragma unroll
  for (int off = 32; off > 0; off >>= 1) {
    s  += __shfl_down(s, off);
    s2 += __shfl_down(s2, off);
  }
  __shared__ float red[8];
  const int wave = tid >> 6, lane = tid & 63;
  if (lane == 0) { red[wave] = s; red[4 + wave] = s2; }
  __syncthreads();
  s  = red[0] + red[1] + red[2] + red[3];
  s2 = red[4] + red[5] + red[6] + red[7];
  const float mu = s * (1.0f / 1024.0f);
  const float rs = rsqrtf(s2 * (1.0f / 1024.0f) - mu * mu + 1e-5f);
  const float4 wv = ((const float4*)w)[tid];
  const float4 bv = ((const float4*)b)[tid];
  bf16x4 o;
  o[0] = (bf16_t)((v.x - mu) * rs * wv.x + bv.x);
  o[1] = (bf16_t)((v.y - mu) * rs * wv.y + bv.y);
  o[2] = (bf16_t)((v.z - mu) * rs * wv.z + bv.z);
  o[3] = (bf16_t)((v.w - mu) * rs * wv.w + bv.w);
  ((bf16x4*)(out + (size_t)row * 1024))[tid] = o;
}

// ---------------- 128x128 GEMM, BK=64, TLP-based (m97 family) ----------------
// EPI 0: +bias -> bf16 | 1: +bias+resid -> f32 | 2: gelu -> bf16 | 3: qkv split
template <int EPI>
__global__ __launch_bounds__(256, 4) void gemm128b(const bf16_t* __restrict__ A,
                                                   const bf16_t* __restrict__ BT,
                                                   const float* __restrict__ bias,
                                                   const float* __restrict__ resid,
                                                   void* __restrict__ out,
                                                   void* __restrict__ out2,
                                                   int M, int N, int K) {
  __shared__ __align__(16) bf16_t sA[128 * 64];
  __shared__ __align__(16) bf16_t sB[128 * 64];
  const int tid = threadIdx.x;
  const int lane = tid & 63, wave = tid >> 6;
  const int wr = wave >> 1, wc = wave & 1;
  const int g = lane >> 4, lr = lane & 15;

  const int bid = blockIdx.x;
  const int cpx = gridDim.x >> 3;
  const int gid = (bid & 7) * cpx + (bid >> 3);
  const int m0 = (gid & 63) * 128, n0 = (gid >> 6) * 128;
  const bf16_t* Ab = A + (size_t)m0 * K;
  const bf16_t* Bb = BT + (size_t)n0 * K;

  f32x4 acc[4][4] = {};

  for (int kt = 0; kt < K; kt += 64) {
    __syncthreads();
#pragma unroll
    for (int q = 0; q < 4; ++q) {
      const int c = q * 256 + tid;
      const int r = c >> 3;
      const int j = (c & 7) ^ (r & 7);
      const size_t doff = (size_t)(q * 256 + wave * 64) * 8;
      gload_lds16(Ab + (size_t)r * K + kt + j * 8, sA + doff);
      gload_lds16(Bb + (size_t)r * K + kt + j * 8, sB + doff);
    }
    __syncthreads();
#pragma unroll
    for (int ks = 0; ks < 2; ++ks) {
      s16x8 af[4], bfr[4];
#pragma unroll
      for (int m = 0; m < 4; ++m) {
        const int r = wr * 64 + m * 16 + lr;
        af[m] = *(const s16x8*)&sA[r * 64 + (((ks << 2) + g) ^ (r & 7)) * 8];
      }
#pragma unroll
      for (int n = 0; n < 4; ++n) {
        const int r = wc * 64 + n * 16 + lr;
        bfr[n] = *(const s16x8*)&sB[r * 64 + (((ks << 2) + g) ^ (r & 7)) * 8];
      }
#pragma unroll
      for (int m = 0; m < 4; ++m)
#pragma unroll
        for (int n = 0; n < 4; ++n)
          acc[m][n] = mfma16(af[m], bfr[n], acc[m][n]);
    }
  }

#pragma unroll
  for (int m = 0; m < 4; ++m)
#pragma unroll
    for (int n = 0; n < 4; ++n) {
      const int col = n0 + wc * 64 + n * 16 + lr;
      const float bv = bias[col];
      const int rrow0 = m0 + wr * 64 + m * 16 + g * 4;
      if (EPI == 3 && col >= 2048) {
        const int col2 = col - 2048;
        bf16x4 pk;
#pragma unroll
        for (int i = 0; i < 4; ++i) pk[i] = (bf16_t)(acc[m][n][i] + bv);
        const size_t didx =
            ((((size_t)(rrow0 >> 11)) * 16 + (col2 >> 6)) * 64 + (col2 & 63)) * 2048 +
            (rrow0 & 2047);
        *(bf16x4*)&((bf16_t*)out2)[didx] = pk;
      } else {
#pragma unroll
        for (int i = 0; i < 4; ++i) {
          const int rrow = rrow0 + i;
          float v = acc[m][n][i] + bv;
          if (EPI == 1) {
            const size_t idx = (size_t)rrow * N + col;
            v += resid[idx];
            ((float*)out)[idx] = v;
          } else if (EPI == 2) {
            v = 0.5f * v * (1.0f + erff(v * 0.70710678118f));
            ((bf16_t*)out)[(size_t)rrow * N + col] = (bf16_t)v;
          } else if (EPI == 3) {
            ((bf16_t*)out)[(size_t)rrow * 2048 + col] = (bf16_t)v;
          } else {
            ((bf16_t*)out)[(size_t)rrow * N + col] = (bf16_t)v;
          }
        }
      }
    }
}

// ---------------- flash attention v3 ----------------
// 128 q-rows/block (32/wave in two 16-row halves), swapped QK^T, exp2-domain
// online softmax with defer-max (T13), rotated-chunk P buffer, setprio (T5).
// qk: bf16 [8192][2048] (q col 0, k col 1024); vt: bf16 [64bh][64d][2048s]
__global__ __launch_bounds__(256) void flash_attn3(const bf16_t* __restrict__ qk,
                                                   const bf16_t* __restrict__ vt,
                                                   bf16_t* __restrict__ O) {
  const int S = 2048;
  const int qt = blockIdx.x;   // 16 q-tiles of 128 rows
  const int bh = blockIdx.y;   // 64 (b,h)
  const int h = bh & 15;
  const size_t rowbase = (size_t)(bh >> 4) * S;
  const int tid = threadIdx.x, lane = tid & 63, wave = tid >> 6;
  const int g = lane >> 4, lr = lane & 15;
  const int q0w = qt * 128 + wave * 32;
  const float c2 = 0.18033688f;  // 0.125 * log2(e)

  __shared__ __align__(16) bf16_t sK[64 * 64];     // [kv][d], XOR-swizzled chunks
  __shared__ __align__(16) bf16_t sVT[64 * 64];    // [d][kv], XOR-swizzled chunks
  __shared__ __align__(16) bf16_t sP[4][16 * 64];  // per-wave P, rotated chunks

  const bf16_t* vtb = vt + (size_t)bh * 64 * 2048;

  // Q fragments for both halves: lane (g,lr) holds Q[q][k=8g+j (+32*st)]
  s16x8 aq[2][2];
#pragma unroll
  for (int hf = 0; hf < 2; ++hf) {
    const bf16_t* qrow = qk + (rowbase + q0w + hf * 16 + lr) * 2048 + h * 64;
    aq[hf][0] = *(const s16x8*)(qrow + g * 8);
    aq[hf][1] = *(const s16x8*)(qrow + 32 + g * 8);
  }

  f32x4 oa[2][4] = {};            // per half: O^T[d=f2*16+4g+i][q=lr]
  float m2[2] = {-1e30f, -1e30f}; // running max, log2-domain
  float lrun[2] = {0.0f, 0.0f};

  for (int kv0 = 0; kv0 < S; kv0 += 64) {
    __syncthreads();
    // stage K [64 kv][64 d] and VT [64 d][64 kv]; swizzled source, linear dest
#pragma unroll
    for (int p = 0; p < 2; ++p) {
      const int c = p * 256 + wave * 64 + lane;
      const int r = c >> 3;
      const int pb = (c & 7) ^ (r & 7);
      char* dK = (char*)sK + (size_t)(p * 256 + wave * 64) * 16;
      char* dV = (char*)sVT + (size_t)(p * 256 + wave * 64) * 16;
      gload_lds16(qk + (rowbase + kv0 + r) * 2048 + 1024 + h * 64 + pb * 8, dK);
      gload_lds16(vtb + (size_t)r * 2048 + kv0 + pb * 8, dV);
    }
    __syncthreads();

#pragma unroll
    for (int hf = 0; hf < 2; ++hf) {
      // swapped QK^T: lane holds S[q=lr][kv=fr*16+4g+i] (raw scores)
      f32x4 sc[4] = {};
      __builtin_amdgcn_s_setprio(1);
#pragma unroll
      for (int st = 0; st < 2; ++st)
#pragma unroll
        for (int fr = 0; fr < 4; ++fr) {
          const int pb = (g + 4 * st) ^ (lr & 7);
          const s16x8 ak = *(const s16x8*)&sK[(fr * 16 + lr) * 64 + pb * 8];
          sc[fr] = mfma16(ak, aq[hf][st], sc[fr]);
        }
      __builtin_amdgcn_s_setprio(0);

      // online softmax in log2-domain; one q-row per lane (4 g-copies)
      float rmax = fmaxf(fmaxf(sc[0][0], sc[0][1]), fmaxf(sc[0][2], sc[0][3]));
#pragma unroll
      for (int fr = 1; fr < 4; ++fr)
#pragma unroll
        for (int i = 0; i < 4; ++i) rmax = fmaxf(rmax, sc[fr][i]);
      rmax = fmaxf(rmax, __shfl_xor(rmax, 16));
      rmax = fmaxf(rmax, __shfl_xor(rmax, 32));
      const float pm2 = rmax * c2;
      // defer-max: only rescale when the max moved materially (wave-uniform)
      if (!__all(pm2 <= m2[hf] + 8.0f)) {
        const float mn = fmaxf(m2[hf], pm2);
        const float alpha = exp2f(m2[hf] - mn);
        m2[hf] = mn;
        lrun[hf] *= alpha;
#pragma unroll
        for (int f2 = 0; f2 < 4; ++f2)
#pragma unroll
          for (int i = 0; i < 4; ++i) oa[hf][f2][i] *= alpha;
      }
      const float mm = m2[hf];
      float rsum = 0.0f;
#pragma unroll
      for (int fr = 0; fr < 4; ++fr)
#pragma unroll
        for (int i = 0; i < 4; ++i) {
          const float pp = exp2f(fmaf(sc[fr][i], c2, -mm));
          sc[fr][i] = pp;
          rsum += pp;
        }
      rsum += __shfl_xor(rsum, 16);
      rsum += __shfl_xor(rsum, 32);
      lrun[hf] += rsum;

      // P[q=lr][kv] -> per-wave LDS, 8-elem chunks rotated by (c+lr)&7
#pragma unroll
      for (int fr = 0; fr < 4; ++fr) {
        bf16x4 pk;
#pragma unroll
        for (int i = 0; i < 4; ++i) pk[i] = (bf16_t)sc[fr][i];
        const int c = fr * 2 + (g >> 1);
        *(bf16x4*)&sP[wave][lr * 64 + ((c + lr) & 7) * 8 + 4 * (g & 1)] = pk;
      }

      // PV: O^T += mfma(VT-frag, P-frag)  (same-wave LDS, in-order, no barrier)
      __builtin_amdgcn_s_setprio(1);
#pragma unroll
      for (int st = 0; st < 2; ++st) {
        const int pc = st * 4 + g;
        const s16x8 pa = *(const s16x8*)&sP[wave][lr * 64 + ((pc + lr) & 7) * 8];
#pragma unroll
        for (int f2 = 0; f2 < 4; ++f2) {
          const int pb = (g + 4 * st) ^ (lr & 7);
          const s16x8 va = *(const s16x8*)&sVT[(f2 * 16 + lr) * 64 + pb * 8];
          oa[hf][f2] = mfma16(va, pa, oa[hf][f2]);
        }
      }
      __builtin_amdgcn_s_setprio(0);
    }
  }

#pragma unroll
  for (int hf = 0; hf < 2; ++hf) {
    const float rl = 1.0f / lrun[hf];
#pragma unroll
    for (int f2 = 0; f2 < 4; ++f2) {
      bf16x4 ov;
#pragma unroll
      for (int i = 0; i < 4; ++i) ov[i] = (bf16_t)(oa[hf][f2][i] * rl);
      *(bf16x4*)&O[(rowbase + q0w + hf * 16 + lr) * 1024 + h * 64 + f2 * 16 + 4 * g] = ov;
    }
  }
}

// ---------------- launch ----------------
extern "C" void kernel_launch(void* const* d_in, const int* in_sizes, int n_in,
                              void* d_out, int out_size, void* d_ws, size_t ws_size,
                              hipStream_t stream) {
  const float* x    = (const float*)d_in[0];
  const float* ln1w = (const float*)d_in[1];
  const float* ln1b = (const float*)d_in[2];
  const float* Wqkv = (const float*)d_in[3];
  const float* bqkv = (const float*)d_in[4];
  const float* Wo   = (const float*)d_in[5];
  const float* bo   = (const float*)d_in[6];
  const float* ln2w = (const float*)d_in[7];
  const float* ln2b = (const float*)d_in[8];
  const float* fc1w = (const float*)d_in[9];
  const float* fc1b = (const float*)d_in[10];
  const float* fc2w = (const float*)d_in[11];
  const float* fc2b = (const float*)d_in[12];

  const int M = 8192;

  char* ws = (char*)d_ws;
  size_t off = 0;
  auto alloc = [&](size_t bytes) {
    char* p = ws + off;
    off += (bytes + 255) & ~(size_t)255;
    return p;
  };
  // persistent weights (bf16, transposed)
  bf16_t* WqkvT = (bf16_t*)alloc((size_t)3072 * 1024 * 2);   // 6 MB
  bf16_t* WoT   = (bf16_t*)alloc((size_t)1024 * 1024 * 2);   // 2 MB
  bf16_t* fc1T  = (bf16_t*)alloc((size_t)4096 * 1024 * 2);   // 8 MB
  bf16_t* fc2T  = (bf16_t*)alloc((size_t)1024 * 4096 * 2);   // 8 MB
  // activations
  bf16_t* h1    = (bf16_t*)alloc((size_t)M * 1024 * 2);      // 16 MB (reused as h2)
  bf16_t* qkQK  = (bf16_t*)alloc((size_t)M * 2048 * 2);      // 32 MB (attn region pt 1)
  bf16_t* vTg   = (bf16_t*)alloc((size_t)M * 1024 * 2);      // 16 MB (pt 2)
  bf16_t* attnO = (bf16_t*)alloc((size_t)M * 1024 * 2);      // 16 MB (pt 3)
  float*  x2    = (float*)alloc((size_t)M * 1024 * 4);       // 32 MB
  // aliases: lifetimes disjoint in stream order
  bf16_t* h2   = h1;     // h1 dead after QKV GEMM
  bf16_t* gbuf = qkQK;   // qkQK/vTg dead after attn, attnO dead after o-proj
  if (off > ws_size) return;  // ~136 MB required

  const dim3 tb(32, 8);
  tcast_kernel<<<dim3(96, 32), tb, 0, stream>>>(Wqkv, WqkvT, 1024, 3072);
  tcast_kernel<<<dim3(32, 32), tb, 0, stream>>>(Wo, WoT, 1024, 1024);
  tcast_kernel<<<dim3(128, 32), tb, 0, stream>>>(fc1w, fc1T, 1024, 4096);
  tcast_kernel<<<dim3(32, 128), tb, 0, stream>>>(fc2w, fc2T, 4096, 1024);

  ln_kernel<<<M, 256, 0, stream>>>(x, ln1w, ln1b, h1);

  gemm128b<3><<<dim3(1536), 256, 0, stream>>>(h1, WqkvT, bqkv, nullptr, qkQK, vTg, M, 3072, 1024);

  flash_attn3<<<dim3(16, 64), 256, 0, stream>>>(qkQK, vTg, attnO);

  gemm128b<1><<<dim3(512), 256, 0, stream>>>(attnO, WoT, bo, x, x2, nullptr, M, 1024, 1024);

  ln_kernel<<<M, 256, 0, stream>>>(x2, ln2w, ln2b, h2);

  gemm128b<2><<<dim3(2048), 256, 0, stream>>>(h2, fc1T, fc1b, nullptr, gbuf, nullptr, M, 4096, 1024);

  gemm128b<1><<<dim3(512), 256, 0, stream>>>(gbuf, fc2T, fc2b, x2, (float*)d_out, nullptr, M, 1024, 4096);
}

// Round 9
// 463.439 us; speedup vs baseline: 1.0176x; 1.0176x over previous
//
#include <hip/hip_runtime.h>
#include <hip/hip_bf16.h>
#include <math.h>

typedef __bf16 bf16_t;
typedef __bf16 bf16x4 __attribute__((ext_vector_type(4)));
typedef short  s16x8  __attribute__((ext_vector_type(8)));
typedef float  f32x4  __attribute__((ext_vector_type(4)));

#define DEVINL __device__ __forceinline__

DEVINL void gload_lds16(const void* g, void* l) {
  __builtin_amdgcn_global_load_lds(
      (const __attribute__((address_space(1))) unsigned int*)g,
      (__attribute__((address_space(3))) unsigned int*)l, 16, 0, 0);
}

DEVINL f32x4 mfma16(s16x8 a, s16x8 b, f32x4 c) {
  return __builtin_amdgcn_mfma_f32_16x16x32_bf16(a, b, c, 0, 0, 0);
}

// ---------------- transpose + cast: W[K][N] f32 -> WT[N][K] bf16 ----------------
__global__ __launch_bounds__(256) void tcast_kernel(const float* __restrict__ W,
                                                    bf16_t* __restrict__ WT,
                                                    int K, int N) {
  __shared__ float tile[32][33];
  const int n0 = blockIdx.x * 32, k0 = blockIdx.y * 32;
  const int tx = threadIdx.x, ty = threadIdx.y;
#pragma unroll
  for (int j = 0; j < 4; ++j)
    tile[ty + j * 8][tx] = W[(size_t)(k0 + ty + j * 8) * N + (n0 + tx)];
  __syncthreads();
#pragma unroll
  for (int j = 0; j < 4; ++j)
    WT[(size_t)(n0 + ty + j * 8) * K + (k0 + tx)] = (bf16_t)tile[tx][ty + j * 8];
}

// ---------------- layernorm: f32 [rows][1024] -> bf16 ----------------
__global__ __launch_bounds__(256) void ln_kernel(const float* __restrict__ x,
                                                 const float* __restrict__ w,
                                                 const float* __restrict__ b,
                                                 bf16_t* __restrict__ out) {
  const int row = blockIdx.x, tid = threadIdx.x;
  const float4 v = ((const float4*)(x + (size_t)row * 1024))[tid];
  float s  = v.x + v.y + v.z + v.w;
  float s2 = v.x * v.x + v.y * v.y + v.z * v.z + v.w * v.w;
#pragma unroll
  for (int off = 32; off > 0; off >>= 1) {
    s  += __shfl_down(s, off);
    s2 += __shfl_down(s2, off);
  }
  __shared__ float red[8];
  const int wave = tid >> 6, lane = tid & 63;
  if (lane == 0) { red[wave] = s; red[4 + wave] = s2; }
  __syncthreads();
  s  = red[0] + red[1] + red[2] + red[3];
  s2 = red[4] + red[5] + red[6] + red[7];
  const float mu = s * (1.0f / 1024.0f);
  const float rs = rsqrtf(s2 * (1.0f / 1024.0f) - mu * mu + 1e-5f);
  const float4 wv = ((const float4*)w)[tid];
  const float4 bv = ((const float4*)b)[tid];
  bf16x4 o;
  o[0] = (bf16_t)((v.x - mu) * rs * wv.x + bv.x);
  o[1] = (bf16_t)((v.y - mu) * rs * wv.y + bv.y);
  o[2] = (bf16_t)((v.z - mu) * rs * wv.z + bv.z);
  o[3] = (bf16_t)((v.w - mu) * rs * wv.w + bv.w);
  ((bf16x4*)(out + (size_t)row * 1024))[tid] = o;
}

// ---------------- 128x128 GEMM, BK=64, TLP-based (m97 family) ----------------
// EPI 0: +bias -> bf16 | 1: +bias+resid -> f32 | 2: gelu -> bf16 | 3: qkv split
template <int EPI>
__global__ __launch_bounds__(256, 4) void gemm128b(const bf16_t* __restrict__ A,
                                                   const bf16_t* __restrict__ BT,
                                                   const float* __restrict__ bias,
                                                   const float* __restrict__ resid,
                                                   void* __restrict__ out,
                                                   void* __restrict__ out2,
                                                   int M, int N, int K) {
  __shared__ __align__(16) bf16_t sA[128 * 64];
  __shared__ __align__(16) bf16_t sB[128 * 64];
  const int tid = threadIdx.x;
  const int lane = tid & 63, wave = tid >> 6;
  const int wr = wave >> 1, wc = wave & 1;
  const int g = lane >> 4, lr = lane & 15;

  const int bid = blockIdx.x;
  const int cpx = gridDim.x >> 3;
  const int gid = (bid & 7) * cpx + (bid >> 3);
  const int m0 = (gid & 63) * 128, n0 = (gid >> 6) * 128;
  const bf16_t* Ab = A + (size_t)m0 * K;
  const bf16_t* Bb = BT + (size_t)n0 * K;

  f32x4 acc[4][4] = {};

  for (int kt = 0; kt < K; kt += 64) {
    __syncthreads();
#pragma unroll
    for (int q = 0; q < 4; ++q) {
      const int c = q * 256 + tid;
      const int r = c >> 3;
      const int j = (c & 7) ^ (r & 7);
      const size_t doff = (size_t)(q * 256 + wave * 64) * 8;
      gload_lds16(Ab + (size_t)r * K + kt + j * 8, sA + doff);
      gload_lds16(Bb + (size_t)r * K + kt + j * 8, sB + doff);
    }
    __syncthreads();
#pragma unroll
    for (int ks = 0; ks < 2; ++ks) {
      s16x8 af[4], bfr[4];
#pragma unroll
      for (int m = 0; m < 4; ++m) {
        const int r = wr * 64 + m * 16 + lr;
        af[m] = *(const s16x8*)&sA[r * 64 + (((ks << 2) + g) ^ (r & 7)) * 8];
      }
#pragma unroll
      for (int n = 0; n < 4; ++n) {
        const int r = wc * 64 + n * 16 + lr;
        bfr[n] = *(const s16x8*)&sB[r * 64 + (((ks << 2) + g) ^ (r & 7)) * 8];
      }
#pragma unroll
      for (int m = 0; m < 4; ++m)
#pragma unroll
        for (int n = 0; n < 4; ++n)
          acc[m][n] = mfma16(af[m], bfr[n], acc[m][n]);
    }
  }

#pragma unroll
  for (int m = 0; m < 4; ++m)
#pragma unroll
    for (int n = 0; n < 4; ++n) {
      const int col = n0 + wc * 64 + n * 16 + lr;
      const float bv = bias[col];
      const int rrow0 = m0 + wr * 64 + m * 16 + g * 4;
      if (EPI == 3 && col >= 2048) {
        const int col2 = col - 2048;
        bf16x4 pk;
#pragma unroll
        for (int i = 0; i < 4; ++i) pk[i] = (bf16_t)(acc[m][n][i] + bv);
        const size_t didx =
            ((((size_t)(rrow0 >> 11)) * 16 + (col2 >> 6)) * 64 + (col2 & 63)) * 2048 +
            (rrow0 & 2047);
        *(bf16x4*)&((bf16_t*)out2)[didx] = pk;
      } else {
#pragma unroll
        for (int i = 0; i < 4; ++i) {
          const int rrow = rrow0 + i;
          float v = acc[m][n][i] + bv;
          if (EPI == 1) {
            const size_t idx = (size_t)rrow * N + col;
            v += resid[idx];
            ((float*)out)[idx] = v;
          } else if (EPI == 2) {
            v = 0.5f * v * (1.0f + erff(v * 0.70710678118f));
            ((bf16_t*)out)[(size_t)rrow * N + col] = (bf16_t)v;
          } else if (EPI == 3) {
            ((bf16_t*)out)[(size_t)rrow * 2048 + col] = (bf16_t)v;
          } else {
            ((bf16_t*)out)[(size_t)rrow * N + col] = (bf16_t)v;
          }
        }
      }
    }
}

// ---------------- flash attention v4 ----------------
// QBLK=64 (16 q-rows/wave, r7 structure) + double-buffered K/V staging with
// prefetch-next-tile (2-phase T3 minimum), exp2-domain softmax with defer-max
// (T13), rotated-chunk P buffer, setprio (T5), hoisted staging pointers.
// qk: bf16 [8192][2048] (q col 0, k col 1024); vt: bf16 [64bh][64d][2048s]
__global__ __launch_bounds__(256) void flash_attn4(const bf16_t* __restrict__ qk,
                                                   const bf16_t* __restrict__ vt,
                                                   bf16_t* __restrict__ O) {
  const int S = 2048;
  const int qt = blockIdx.x;   // 32 q-tiles of 64 rows
  const int bh = blockIdx.y;   // 64 (b,h)
  const int h = bh & 15;
  const size_t rowbase = (size_t)(bh >> 4) * S;
  const int tid = threadIdx.x, lane = tid & 63, wave = tid >> 6;
  const int g = lane >> 4, lr = lane & 15;
  const int q0w = qt * 64 + wave * 16;
  const float c2 = 0.18033688f;  // 0.125 * log2(e)

  __shared__ __align__(16) bf16_t sK[2][64 * 64];   // [kv][d], XOR-swizzled chunks
  __shared__ __align__(16) bf16_t sVT[2][64 * 64];  // [d][kv], XOR-swizzled chunks
  __shared__ __align__(16) bf16_t sP[4][16 * 64];   // per-wave P, rotated chunks

  const bf16_t* vtb = vt + (size_t)bh * 64 * 2048;

  // hoisted per-thread staging sources (advance by tile via kvoff)
  const bf16_t* kp[2];
  const bf16_t* vp[2];
  int ldsoff[2];
#pragma unroll
  for (int p = 0; p < 2; ++p) {
    const int cp = p * 256 + wave * 64 + lane;
    const int r = cp >> 3;
    const int pb = (cp & 7) ^ (r & 7);
    kp[p] = qk + (rowbase + r) * 2048 + 1024 + h * 64 + pb * 8;
    vp[p] = vtb + (size_t)r * 2048 + pb * 8;
    ldsoff[p] = (p * 256 + wave * 64) * 16;  // byte offset of this wave's segment
  }
  auto stage = [&](int t, int buf) {
    const int kvoff = t << 6;
#pragma unroll
    for (int p = 0; p < 2; ++p) {
      gload_lds16(kp[p] + (size_t)kvoff * 2048, (char*)sK[buf] + ldsoff[p]);
      gload_lds16(vp[p] + kvoff, (char*)sVT[buf] + ldsoff[p]);
    }
  };

  // Q fragments: lane (g,lr) holds Q[q=lr][k=8g+j (+32*st)]
  s16x8 aq[2];
  {
    const bf16_t* qrow = qk + (rowbase + q0w + lr) * 2048 + h * 64;
    aq[0] = *(const s16x8*)(qrow + g * 8);
    aq[1] = *(const s16x8*)(qrow + 32 + g * 8);
  }

  f32x4 oa[4] = {};               // O^T[d=f2*16+4g+i][q=lr]
  float m2 = -1e30f, lrun = 0.0f; // running max (log2-domain), denom

  stage(0, 0);

  for (int t = 0; t < 32; ++t) {
    const int cur = t & 1;
    // drains tile t's staged loads (vmcnt) + barrier; all waves done with buf^1
    __syncthreads();
    if (t + 1 < 32) stage(t + 1, cur ^ 1);  // overlaps with compute below

    // swapped QK^T: lane holds S[q=lr][kv=fr*16+4g+i] (raw scores)
    f32x4 sc[4] = {};
    __builtin_amdgcn_s_setprio(1);
#pragma unroll
    for (int st = 0; st < 2; ++st)
#pragma unroll
      for (int fr = 0; fr < 4; ++fr) {
        const int pb = (g + 4 * st) ^ (lr & 7);
        const s16x8 ak = *(const s16x8*)&sK[cur][(fr * 16 + lr) * 64 + pb * 8];
        sc[fr] = mfma16(ak, aq[st], sc[fr]);
      }
    __builtin_amdgcn_s_setprio(0);

    // online softmax in log2-domain, defer-max (T13)
    float rmax = fmaxf(fmaxf(sc[0][0], sc[0][1]), fmaxf(sc[0][2], sc[0][3]));
#pragma unroll
    for (int fr = 1; fr < 4; ++fr)
#pragma unroll
      for (int i = 0; i < 4; ++i) rmax = fmaxf(rmax, sc[fr][i]);
    rmax = fmaxf(rmax, __shfl_xor(rmax, 16));
    rmax = fmaxf(rmax, __shfl_xor(rmax, 32));
    const float pm2 = rmax * c2;
    if (!__all(pm2 <= m2 + 8.0f)) {
      const float mn = fmaxf(m2, pm2);
      const float alpha = exp2f(m2 - mn);
      m2 = mn;
      lrun *= alpha;
#pragma unroll
      for (int f2 = 0; f2 < 4; ++f2)
#pragma unroll
        for (int i = 0; i < 4; ++i) oa[f2][i] *= alpha;
    }
    float rsum = 0.0f;
#pragma unroll
    for (int fr = 0; fr < 4; ++fr)
#pragma unroll
      for (int i = 0; i < 4; ++i) {
        const float pp = exp2f(fmaf(sc[fr][i], c2, -m2));
        sc[fr][i] = pp;
        rsum += pp;
      }
    rsum += __shfl_xor(rsum, 16);
    rsum += __shfl_xor(rsum, 32);
    lrun += rsum;

    // P[q=lr][kv] -> per-wave LDS, 8-elem chunks rotated by (c+lr)&7
#pragma unroll
    for (int fr = 0; fr < 4; ++fr) {
      bf16x4 pk;
#pragma unroll
      for (int i = 0; i < 4; ++i) pk[i] = (bf16_t)sc[fr][i];
      const int c = fr * 2 + (g >> 1);
      *(bf16x4*)&sP[wave][lr * 64 + ((c + lr) & 7) * 8 + 4 * (g & 1)] = pk;
    }

    // PV: O^T += mfma(VT-frag, P-frag)  (same-wave LDS, in-order)
    __builtin_amdgcn_s_setprio(1);
#pragma unroll
    for (int st = 0; st < 2; ++st) {
      const int pc = st * 4 + g;
      const s16x8 pa = *(const s16x8*)&sP[wave][lr * 64 + ((pc + lr) & 7) * 8];
#pragma unroll
      for (int f2 = 0; f2 < 4; ++f2) {
        const int pb = (g + 4 * st) ^ (lr & 7);
        const s16x8 va = *(const s16x8*)&sVT[cur][(f2 * 16 + lr) * 64 + pb * 8];
        oa[f2] = mfma16(va, pa, oa[f2]);
      }
    }
    __builtin_amdgcn_s_setprio(0);
  }

  const float rl = 1.0f / lrun;
#pragma unroll
  for (int f2 = 0; f2 < 4; ++f2) {
    bf16x4 ov;
#pragma unroll
    for (int i = 0; i < 4; ++i) ov[i] = (bf16_t)(oa[f2][i] * rl);
    *(bf16x4*)&O[(rowbase + q0w + lr) * 1024 + h * 64 + f2 * 16 + 4 * g] = ov;
  }
}

// ---------------- launch ----------------
extern "C" void kernel_launch(void* const* d_in, const int* in_sizes, int n_in,
                              void* d_out, int out_size, void* d_ws, size_t ws_size,
                              hipStream_t stream) {
  const float* x    = (const float*)d_in[0];
  const float* ln1w = (const float*)d_in[1];
  const float* ln1b = (const float*)d_in[2];
  const float* Wqkv = (const float*)d_in[3];
  const float* bqkv = (const float*)d_in[4];
  const float* Wo   = (const float*)d_in[5];
  const float* bo   = (const float*)d_in[6];
  const float* ln2w = (const float*)d_in[7];
  const float* ln2b = (const float*)d_in[8];
  const float* fc1w = (const float*)d_in[9];
  const float* fc1b = (const float*)d_in[10];
  const float* fc2w = (const float*)d_in[11];
  const float* fc2b = (const float*)d_in[12];

  const int M = 8192;

  char* ws = (char*)d_ws;
  size_t off = 0;
  auto alloc = [&](size_t bytes) {
    char* p = ws + off;
    off += (bytes + 255) & ~(size_t)255;
    return p;
  };
  // persistent weights (bf16, transposed)
  bf16_t* WqkvT = (bf16_t*)alloc((size_t)3072 * 1024 * 2);   // 6 MB
  bf16_t* WoT   = (bf16_t*)alloc((size_t)1024 * 1024 * 2);   // 2 MB
  bf16_t* fc1T  = (bf16_t*)alloc((size_t)4096 * 1024 * 2);   // 8 MB
  bf16_t* fc2T  = (bf16_t*)alloc((size_t)1024 * 4096 * 2);   // 8 MB
  // activations
  bf16_t* h1    = (bf16_t*)alloc((size_t)M * 1024 * 2);      // 16 MB (reused as h2)
  bf16_t* qkQK  = (bf16_t*)alloc((size_t)M * 2048 * 2);      // 32 MB (attn region pt 1)
  bf16_t* vTg   = (bf16_t*)alloc((size_t)M * 1024 * 2);      // 16 MB (pt 2)
  bf16_t* attnO = (bf16_t*)alloc((size_t)M * 1024 * 2);      // 16 MB (pt 3)
  float*  x2    = (float*)alloc((size_t)M * 1024 * 4);       // 32 MB
  // aliases: lifetimes disjoint in stream order
  bf16_t* h2   = h1;     // h1 dead after QKV GEMM
  bf16_t* gbuf = qkQK;   // qkQK/vTg dead after attn, attnO dead after o-proj
  if (off > ws_size) return;  // ~136 MB required

  const dim3 tb(32, 8);
  tcast_kernel<<<dim3(96, 32), tb, 0, stream>>>(Wqkv, WqkvT, 1024, 3072);
  tcast_kernel<<<dim3(32, 32), tb, 0, stream>>>(Wo, WoT, 1024, 1024);
  tcast_kernel<<<dim3(128, 32), tb, 0, stream>>>(fc1w, fc1T, 1024, 4096);
  tcast_kernel<<<dim3(32, 128), tb, 0, stream>>>(fc2w, fc2T, 4096, 1024);

  ln_kernel<<<M, 256, 0, stream>>>(x, ln1w, ln1b, h1);

  gemm128b<3><<<dim3(1536), 256, 0, stream>>>(h1, WqkvT, bqkv, nullptr, qkQK, vTg, M, 3072, 1024);

  flash_attn4<<<dim3(32, 64), 256, 0, stream>>>(qkQK, vTg, attnO);

  gemm128b<1><<<dim3(512), 256, 0, stream>>>(attnO, WoT, bo, x, x2, nullptr, M, 1024, 1024);

  ln_kernel<<<M, 256, 0, stream>>>(x2, ln2w, ln2b, h2);

  gemm128b<2><<<dim3(2048), 256, 0, stream>>>(h2, fc1T, fc1b, nullptr, gbuf, nullptr, M, 4096, 1024);

  gemm128b<1><<<dim3(512), 256, 0, stream>>>(gbuf, fc2T, fc2b, x2, (float*)d_out, nullptr, M, 1024, 4096);
}

// Round 10
// 461.064 us; speedup vs baseline: 1.0229x; 1.0052x over previous
//
#include <hip/hip_runtime.h>
#include <hip/hip_bf16.h>
#include <math.h>

typedef __bf16 bf16_t;
typedef __bf16 bf16x4 __attribute__((ext_vector_type(4)));
typedef short  s16x8  __attribute__((ext_vector_type(8)));
typedef float  f32x4  __attribute__((ext_vector_type(4)));

#define DEVINL __device__ __forceinline__

DEVINL void gload_lds16(const void* g, void* l) {
  __builtin_amdgcn_global_load_lds(
      (const __attribute__((address_space(1))) unsigned int*)g,
      (__attribute__((address_space(3))) unsigned int*)l, 16, 0, 0);
}

DEVINL f32x4 mfma16(s16x8 a, s16x8 b, f32x4 c) {
  return __builtin_amdgcn_mfma_f32_16x16x32_bf16(a, b, c, 0, 0, 0);
}

// ---------------- transpose + cast: W[K][N] f32 -> WT[N][K] bf16 ----------------
__global__ __launch_bounds__(256) void tcast_kernel(const float* __restrict__ W,
                                                    bf16_t* __restrict__ WT,
                                                    int K, int N) {
  __shared__ float tile[32][33];
  const int n0 = blockIdx.x * 32, k0 = blockIdx.y * 32;
  const int tx = threadIdx.x, ty = threadIdx.y;
#pragma unroll
  for (int j = 0; j < 4; ++j)
    tile[ty + j * 8][tx] = W[(size_t)(k0 + ty + j * 8) * N + (n0 + tx)];
  __syncthreads();
#pragma unroll
  for (int j = 0; j < 4; ++j)
    WT[(size_t)(n0 + ty + j * 8) * K + (k0 + tx)] = (bf16_t)tile[tx][ty + j * 8];
}

// ---------------- layernorm: f32 [rows][1024] -> bf16 ----------------
__global__ __launch_bounds__(256) void ln_kernel(const float* __restrict__ x,
                                                 const float* __restrict__ w,
                                                 const float* __restrict__ b,
                                                 bf16_t* __restrict__ out) {
  const int row = blockIdx.x, tid = threadIdx.x;
  const float4 v = ((const float4*)(x + (size_t)row * 1024))[tid];
  float s  = v.x + v.y + v.z + v.w;
  float s2 = v.x * v.x + v.y * v.y + v.z * v.z + v.w * v.w;
#pragma unroll
  for (int off = 32; off > 0; off >>= 1) {
    s  += __shfl_down(s, off);
    s2 += __shfl_down(s2, off);
  }
  __shared__ float red[8];
  const int wave = tid >> 6, lane = tid & 63;
  if (lane == 0) { red[wave] = s; red[4 + wave] = s2; }
  __syncthreads();
  s  = red[0] + red[1] + red[2] + red[3];
  s2 = red[4] + red[5] + red[6] + red[7];
  const float mu = s * (1.0f / 1024.0f);
  const float rs = rsqrtf(s2 * (1.0f / 1024.0f) - mu * mu + 1e-5f);
  const float4 wv = ((const float4*)w)[tid];
  const float4 bv = ((const float4*)b)[tid];
  bf16x4 o;
  o[0] = (bf16_t)((v.x - mu) * rs * wv.x + bv.x);
  o[1] = (bf16_t)((v.y - mu) * rs * wv.y + bv.y);
  o[2] = (bf16_t)((v.z - mu) * rs * wv.z + bv.z);
  o[3] = (bf16_t)((v.w - mu) * rs * wv.w + bv.w);
  ((bf16x4*)(out + (size_t)row * 1024))[tid] = o;
}

// ---------------- 128x128 GEMM, BK=64, TLP-based (m97 family) ----------------
// EPI 0: +bias -> bf16 | 1: +bias+resid -> f32 | 2: gelu -> bf16 | 3: qkv split
template <int EPI>
__global__ __launch_bounds__(256, 4) void gemm128b(const bf16_t* __restrict__ A,
                                                   const bf16_t* __restrict__ BT,
                                                   const float* __restrict__ bias,
                                                   const float* __restrict__ resid,
                                                   void* __restrict__ out,
                                                   void* __restrict__ out2,
                                                   int M, int N, int K) {
  __shared__ __align__(16) bf16_t sA[128 * 64];
  __shared__ __align__(16) bf16_t sB[128 * 64];
  const int tid = threadIdx.x;
  const int lane = tid & 63, wave = tid >> 6;
  const int wr = wave >> 1, wc = wave & 1;
  const int g = lane >> 4, lr = lane & 15;

  const int bid = blockIdx.x;
  const int cpx = gridDim.x >> 3;
  const int gid = (bid & 7) * cpx + (bid >> 3);
  const int m0 = (gid & 63) * 128, n0 = (gid >> 6) * 128;
  const bf16_t* Ab = A + (size_t)m0 * K;
  const bf16_t* Bb = BT + (size_t)n0 * K;

  f32x4 acc[4][4] = {};

  for (int kt = 0; kt < K; kt += 64) {
    __syncthreads();
#pragma unroll
    for (int q = 0; q < 4; ++q) {
      const int c = q * 256 + tid;
      const int r = c >> 3;
      const int j = (c & 7) ^ (r & 7);
      const size_t doff = (size_t)(q * 256 + wave * 64) * 8;
      gload_lds16(Ab + (size_t)r * K + kt + j * 8, sA + doff);
      gload_lds16(Bb + (size_t)r * K + kt + j * 8, sB + doff);
    }
    __syncthreads();
#pragma unroll
    for (int ks = 0; ks < 2; ++ks) {
      s16x8 af[4], bfr[4];
#pragma unroll
      for (int m = 0; m < 4; ++m) {
        const int r = wr * 64 + m * 16 + lr;
        af[m] = *(const s16x8*)&sA[r * 64 + (((ks << 2) + g) ^ (r & 7)) * 8];
      }
#pragma unroll
      for (int n = 0; n < 4; ++n) {
        const int r = wc * 64 + n * 16 + lr;
        bfr[n] = *(const s16x8*)&sB[r * 64 + (((ks << 2) + g) ^ (r & 7)) * 8];
      }
#pragma unroll
      for (int m = 0; m < 4; ++m)
#pragma unroll
        for (int n = 0; n < 4; ++n)
          acc[m][n] = mfma16(af[m], bfr[n], acc[m][n]);
    }
  }

#pragma unroll
  for (int m = 0; m < 4; ++m)
#pragma unroll
    for (int n = 0; n < 4; ++n) {
      const int col = n0 + wc * 64 + n * 16 + lr;
      const float bv = bias[col];
      const int rrow0 = m0 + wr * 64 + m * 16 + g * 4;
      if (EPI == 3 && col >= 2048) {
        const int col2 = col - 2048;
        bf16x4 pk;
#pragma unroll
        for (int i = 0; i < 4; ++i) pk[i] = (bf16_t)(acc[m][n][i] + bv);
        const size_t didx =
            ((((size_t)(rrow0 >> 11)) * 16 + (col2 >> 6)) * 64 + (col2 & 63)) * 2048 +
            (rrow0 & 2047);
        *(bf16x4*)&((bf16_t*)out2)[didx] = pk;
      } else {
#pragma unroll
        for (int i = 0; i < 4; ++i) {
          const int rrow = rrow0 + i;
          float v = acc[m][n][i] + bv;
          if (EPI == 1) {
            const size_t idx = (size_t)rrow * N + col;
            v += resid[idx];
            ((float*)out)[idx] = v;
          } else if (EPI == 2) {
            v = 0.5f * v * (1.0f + erff(v * 0.70710678118f));
            ((bf16_t*)out)[(size_t)rrow * N + col] = (bf16_t)v;
          } else if (EPI == 3) {
            ((bf16_t*)out)[(size_t)rrow * 2048 + col] = (bf16_t)v;
          } else {
            ((bf16_t*)out)[(size_t)rrow * N + col] = (bf16_t)v;
          }
        }
      }
    }
}

// ---------------- flash attention v5 ----------------
// EXACTLY the r7 winner's structure (single-buffer 25.6KB LDS, 6 blocks/CU,
// no setprio, pad-72 P) with only the proven VALU cuts: exp2-domain online
// softmax + defer-max (T13).
// qk: bf16 [8192][2048] (q col 0, k col 1024); vt: bf16 [64bh][64d][2048s]
__global__ __launch_bounds__(256) void flash_attn5(const bf16_t* __restrict__ qk,
                                                   const bf16_t* __restrict__ vt,
                                                   bf16_t* __restrict__ O) {
  const int S = 2048;
  const int qt = blockIdx.x;   // 32 q-tiles of 64 rows
  const int bh = blockIdx.y;   // 64 (b,h)
  const int h = bh & 15;
  const size_t rowbase = (size_t)(bh >> 4) * S;
  const int tid = threadIdx.x, lane = tid & 63, wave = tid >> 6;
  const int g = lane >> 4, lr = lane & 15;
  const int q0w = qt * 64 + wave * 16;
  const float c2 = 0.18033688f;  // 0.125 * log2(e)

  __shared__ __align__(16) bf16_t sK[64 * 64];    // [kv][d], XOR-swizzled chunks
  __shared__ __align__(16) bf16_t sVT[64 * 64];   // [d][kv], XOR-swizzled chunks
  __shared__ __align__(16) bf16_t sP[4][16 * 72]; // per-wave P[q][kv], pad 72

  const bf16_t* vtb = vt + (size_t)bh * 64 * 2048;

  // Q fragments: lane (g,lr) holds Q[q=lr][k=8g+j (+32*st)]
  s16x8 aq[2];
  {
    const bf16_t* qrow = qk + (rowbase + q0w + lr) * 2048 + h * 64;
    aq[0] = *(const s16x8*)(qrow + g * 8);
    aq[1] = *(const s16x8*)(qrow + 32 + g * 8);
  }

  f32x4 oa[4] = {};               // O^T[d=f2*16+4g+i][q=lr]
  float m2 = -1e30f, lrun = 0.0f; // running max (log2-domain), denom

  for (int kv0 = 0; kv0 < S; kv0 += 64) {
    __syncthreads();
    // stage K [64 kv][64 d] and VT [64 d][64 kv]; swizzled source, linear dest
#pragma unroll
    for (int p = 0; p < 2; ++p) {
      const int c = p * 256 + wave * 64 + lane;
      const int r = c >> 3;
      const int pb = (c & 7) ^ (r & 7);
      char* dK = (char*)sK + (size_t)(p * 256 + wave * 64) * 16;
      char* dV = (char*)sVT + (size_t)(p * 256 + wave * 64) * 16;
      gload_lds16(qk + (rowbase + kv0 + r) * 2048 + 1024 + h * 64 + pb * 8, dK);
      gload_lds16(vtb + (size_t)r * 2048 + kv0 + pb * 8, dV);
    }
    __syncthreads();

    // swapped QK^T: lane holds S[q=lr][kv=fr*16+4g+i] (raw scores)
    f32x4 sc[4] = {};
#pragma unroll
    for (int st = 0; st < 2; ++st)
#pragma unroll
      for (int fr = 0; fr < 4; ++fr) {
        const int pb = (g + 4 * st) ^ (lr & 7);
        const s16x8 ak = *(const s16x8*)&sK[(fr * 16 + lr) * 64 + pb * 8];
        sc[fr] = mfma16(ak, aq[st], sc[fr]);
      }

    // online softmax in log2-domain with defer-max (T13)
    float rmax = fmaxf(fmaxf(sc[0][0], sc[0][1]), fmaxf(sc[0][2], sc[0][3]));
#pragma unroll
    for (int fr = 1; fr < 4; ++fr)
#pragma unroll
      for (int i = 0; i < 4; ++i) rmax = fmaxf(rmax, sc[fr][i]);
    rmax = fmaxf(rmax, __shfl_xor(rmax, 16));
    rmax = fmaxf(rmax, __shfl_xor(rmax, 32));
    const float pm2 = rmax * c2;
    if (!__all(pm2 <= m2 + 8.0f)) {
      const float mn = fmaxf(m2, pm2);
      const float alpha = exp2f(m2 - mn);
      m2 = mn;
      lrun *= alpha;
#pragma unroll
      for (int f2 = 0; f2 < 4; ++f2)
#pragma unroll
        for (int i = 0; i < 4; ++i) oa[f2][i] *= alpha;
    }
    float rsum = 0.0f;
#pragma unroll
    for (int fr = 0; fr < 4; ++fr)
#pragma unroll
      for (int i = 0; i < 4; ++i) {
        const float pp = exp2f(fmaf(sc[fr][i], c2, -m2));
        sc[fr][i] = pp;
        rsum += pp;
      }
    rsum += __shfl_xor(rsum, 16);
    rsum += __shfl_xor(rsum, 32);
    lrun += rsum;

    // P[q=lr][kv]: in-lane kv-contiguous -> vectorized b64 writes (per-wave LDS)
#pragma unroll
    for (int fr = 0; fr < 4; ++fr) {
      bf16x4 pk;
#pragma unroll
      for (int i = 0; i < 4; ++i) pk[i] = (bf16_t)sc[fr][i];
      *(bf16x4*)&sP[wave][lr * 72 + fr * 16 + 4 * g] = pk;
    }

    // PV: O^T += mfma(VT-frag, P-frag)  (same-wave LDS, in-order, no barrier)
#pragma unroll
    for (int st = 0; st < 2; ++st) {
      const s16x8 pa = *(const s16x8*)&sP[wave][lr * 72 + st * 32 + g * 8];
#pragma unroll
      for (int f2 = 0; f2 < 4; ++f2) {
        const int pb = (g + 4 * st) ^ (lr & 7);
        const s16x8 va = *(const s16x8*)&sVT[(f2 * 16 + lr) * 64 + pb * 8];
        oa[f2] = mfma16(va, pa, oa[f2]);
      }
    }
  }

  const float rl = 1.0f / lrun;
#pragma unroll
  for (int f2 = 0; f2 < 4; ++f2) {
    bf16x4 ov;
#pragma unroll
    for (int i = 0; i < 4; ++i) ov[i] = (bf16_t)(oa[f2][i] * rl);
    *(bf16x4*)&O[(rowbase + q0w + lr) * 1024 + h * 64 + f2 * 16 + 4 * g] = ov;
  }
}

// ---------------- launch ----------------
extern "C" void kernel_launch(void* const* d_in, const int* in_sizes, int n_in,
                              void* d_out, int out_size, void* d_ws, size_t ws_size,
                              hipStream_t stream) {
  const float* x    = (const float*)d_in[0];
  const float* ln1w = (const float*)d_in[1];
  const float* ln1b = (const float*)d_in[2];
  const float* Wqkv = (const float*)d_in[3];
  const float* bqkv = (const float*)d_in[4];
  const float* Wo   = (const float*)d_in[5];
  const float* bo   = (const float*)d_in[6];
  const float* ln2w = (const float*)d_in[7];
  const float* ln2b = (const float*)d_in[8];
  const float* fc1w = (const float*)d_in[9];
  const float* fc1b = (const float*)d_in[10];
  const float* fc2w = (const float*)d_in[11];
  const float* fc2b = (const float*)d_in[12];

  const int M = 8192;

  char* ws = (char*)d_ws;
  size_t off = 0;
  auto alloc = [&](size_t bytes) {
    char* p = ws + off;
    off += (bytes + 255) & ~(size_t)255;
    return p;
  };
  // persistent weights (bf16, transposed)
  bf16_t* WqkvT = (bf16_t*)alloc((size_t)3072 * 1024 * 2);   // 6 MB
  bf16_t* WoT   = (bf16_t*)alloc((size_t)1024 * 1024 * 2);   // 2 MB
  bf16_t* fc1T  = (bf16_t*)alloc((size_t)4096 * 1024 * 2);   // 8 MB
  bf16_t* fc2T  = (bf16_t*)alloc((size_t)1024 * 4096 * 2);   // 8 MB
  // activations
  bf16_t* h1    = (bf16_t*)alloc((size_t)M * 1024 * 2);      // 16 MB (reused as h2)
  bf16_t* qkQK  = (bf16_t*)alloc((size_t)M * 2048 * 2);      // 32 MB (attn region pt 1)
  bf16_t* vTg   = (bf16_t*)alloc((size_t)M * 1024 * 2);      // 16 MB (pt 2)
  bf16_t* attnO = (bf16_t*)alloc((size_t)M * 1024 * 2);      // 16 MB (pt 3)
  float*  x2    = (float*)alloc((size_t)M * 1024 * 4);       // 32 MB
  // aliases: lifetimes disjoint in stream order
  bf16_t* h2   = h1;     // h1 dead after QKV GEMM
  bf16_t* gbuf = qkQK;   // qkQK/vTg dead after attn, attnO dead after o-proj
  if (off > ws_size) return;  // ~136 MB required

  const dim3 tb(32, 8);
  tcast_kernel<<<dim3(96, 32), tb, 0, stream>>>(Wqkv, WqkvT, 1024, 3072);
  tcast_kernel<<<dim3(32, 32), tb, 0, stream>>>(Wo, WoT, 1024, 1024);
  tcast_kernel<<<dim3(128, 32), tb, 0, stream>>>(fc1w, fc1T, 1024, 4096);
  tcast_kernel<<<dim3(32, 128), tb, 0, stream>>>(fc2w, fc2T, 4096, 1024);

  ln_kernel<<<M, 256, 0, stream>>>(x, ln1w, ln1b, h1);

  gemm128b<3><<<dim3(1536), 256, 0, stream>>>(h1, WqkvT, bqkv, nullptr, qkQK, vTg, M, 3072, 1024);

  flash_attn5<<<dim3(32, 64), 256, 0, stream>>>(qkQK, vTg, attnO);

  gemm128b<1><<<dim3(512), 256, 0, stream>>>(attnO, WoT, bo, x, x2, nullptr, M, 1024, 1024);

  ln_kernel<<<M, 256, 0, stream>>>(x2, ln2w, ln2b, h2);

  gemm128b<2><<<dim3(2048), 256, 0, stream>>>(h2, fc1T, fc1b, nullptr, gbuf, nullptr, M, 4096, 1024);

  gemm128b<1><<<dim3(512), 256, 0, stream>>>(gbuf, fc2T, fc2b, x2, (float*)d_out, nullptr, M, 1024, 4096);
}

// Round 11
// 440.218 us; speedup vs baseline: 1.0713x; 1.0474x over previous
//
#include <hip/hip_runtime.h>
#include <hip/hip_bf16.h>
#include <math.h>

typedef __bf16 bf16_t;
typedef __bf16 bf16x4 __attribute__((ext_vector_type(4)));
typedef short  s16x8  __attribute__((ext_vector_type(8)));
typedef float  f32x4  __attribute__((ext_vector_type(4)));

#define DEVINL __device__ __forceinline__

DEVINL void gload_lds16(const void* g, void* l) {
  __builtin_amdgcn_global_load_lds(
      (const __attribute__((address_space(1))) unsigned int*)g,
      (__attribute__((address_space(3))) unsigned int*)l, 16, 0, 0);
}

DEVINL f32x4 mfma16(s16x8 a, s16x8 b, f32x4 c) {
  return __builtin_amdgcn_mfma_f32_16x16x32_bf16(a, b, c, 0, 0, 0);
}

DEVINL float fexp2(float x) { return __builtin_amdgcn_exp2f(x); }  // native v_exp_f32

// ---------------- transpose + cast: W[K][N] f32 -> WT[N][K] bf16 ----------------
__global__ __launch_bounds__(256) void tcast_kernel(const float* __restrict__ W,
                                                    bf16_t* __restrict__ WT,
                                                    int K, int N) {
  __shared__ float tile[32][33];
  const int n0 = blockIdx.x * 32, k0 = blockIdx.y * 32;
  const int tx = threadIdx.x, ty = threadIdx.y;
#pragma unroll
  for (int j = 0; j < 4; ++j)
    tile[ty + j * 8][tx] = W[(size_t)(k0 + ty + j * 8) * N + (n0 + tx)];
  __syncthreads();
#pragma unroll
  for (int j = 0; j < 4; ++j)
    WT[(size_t)(n0 + ty + j * 8) * K + (k0 + tx)] = (bf16_t)tile[tx][ty + j * 8];
}

// ---------------- layernorm: f32 [rows][1024] -> bf16 ----------------
__global__ __launch_bounds__(256) void ln_kernel(const float* __restrict__ x,
                                                 const float* __restrict__ w,
                                                 const float* __restrict__ b,
                                                 bf16_t* __restrict__ out) {
  const int row = blockIdx.x, tid = threadIdx.x;
  const float4 v = ((const float4*)(x + (size_t)row * 1024))[tid];
  float s  = v.x + v.y + v.z + v.w;
  float s2 = v.x * v.x + v.y * v.y + v.z * v.z + v.w * v.w;
#pragma unroll
  for (int off = 32; off > 0; off >>= 1) {
    s  += __shfl_down(s, off);
    s2 += __shfl_down(s2, off);
  }
  __shared__ float red[8];
  const int wave = tid >> 6, lane = tid & 63;
  if (lane == 0) { red[wave] = s; red[4 + wave] = s2; }
  __syncthreads();
  s  = red[0] + red[1] + red[2] + red[3];
  s2 = red[4] + red[5] + red[6] + red[7];
  const float mu = s * (1.0f / 1024.0f);
  const float rs = rsqrtf(s2 * (1.0f / 1024.0f) - mu * mu + 1e-5f);
  const float4 wv = ((const float4*)w)[tid];
  const float4 bv = ((const float4*)b)[tid];
  bf16x4 o;
  o[0] = (bf16_t)((v.x - mu) * rs * wv.x + bv.x);
  o[1] = (bf16_t)((v.y - mu) * rs * wv.y + bv.y);
  o[2] = (bf16_t)((v.z - mu) * rs * wv.z + bv.z);
  o[3] = (bf16_t)((v.w - mu) * rs * wv.w + bv.w);
  ((bf16x4*)(out + (size_t)row * 1024))[tid] = o;
}

// ---------------- 128x128 GEMM, BK=64, TLP-based (m97 family) ----------------
// EPI 0: +bias -> bf16 | 1: +bias+resid -> f32 | 2: gelu -> bf16 | 3: qkv split
template <int EPI>
__global__ __launch_bounds__(256, 4) void gemm128b(const bf16_t* __restrict__ A,
                                                   const bf16_t* __restrict__ BT,
                                                   const float* __restrict__ bias,
                                                   const float* __restrict__ resid,
                                                   void* __restrict__ out,
                                                   void* __restrict__ out2,
                                                   int M, int N, int K) {
  __shared__ __align__(16) bf16_t sA[128 * 64];
  __shared__ __align__(16) bf16_t sB[128 * 64];
  const int tid = threadIdx.x;
  const int lane = tid & 63, wave = tid >> 6;
  const int wr = wave >> 1, wc = wave & 1;
  const int g = lane >> 4, lr = lane & 15;

  const int bid = blockIdx.x;
  const int cpx = gridDim.x >> 3;
  const int gid = (bid & 7) * cpx + (bid >> 3);
  const int m0 = (gid & 63) * 128, n0 = (gid >> 6) * 128;
  const bf16_t* Ab = A + (size_t)m0 * K;
  const bf16_t* Bb = BT + (size_t)n0 * K;

  f32x4 acc[4][4] = {};

  for (int kt = 0; kt < K; kt += 64) {
    __syncthreads();
#pragma unroll
    for (int q = 0; q < 4; ++q) {
      const int c = q * 256 + tid;
      const int r = c >> 3;
      const int j = (c & 7) ^ (r & 7);
      const size_t doff = (size_t)(q * 256 + wave * 64) * 8;
      gload_lds16(Ab + (size_t)r * K + kt + j * 8, sA + doff);
      gload_lds16(Bb + (size_t)r * K + kt + j * 8, sB + doff);
    }
    __syncthreads();
#pragma unroll
    for (int ks = 0; ks < 2; ++ks) {
      s16x8 af[4], bfr[4];
#pragma unroll
      for (int m = 0; m < 4; ++m) {
        const int r = wr * 64 + m * 16 + lr;
        af[m] = *(const s16x8*)&sA[r * 64 + (((ks << 2) + g) ^ (r & 7)) * 8];
      }
#pragma unroll
      for (int n = 0; n < 4; ++n) {
        const int r = wc * 64 + n * 16 + lr;
        bfr[n] = *(const s16x8*)&sB[r * 64 + (((ks << 2) + g) ^ (r & 7)) * 8];
      }
#pragma unroll
      for (int m = 0; m < 4; ++m)
#pragma unroll
        for (int n = 0; n < 4; ++n)
          acc[m][n] = mfma16(af[m], bfr[n], acc[m][n]);
    }
  }

#pragma unroll
  for (int m = 0; m < 4; ++m)
#pragma unroll
    for (int n = 0; n < 4; ++n) {
      const int col = n0 + wc * 64 + n * 16 + lr;
      const float bv = bias[col];
      const int rrow0 = m0 + wr * 64 + m * 16 + g * 4;
      if (EPI == 3 && col >= 2048) {
        const int col2 = col - 2048;
        bf16x4 pk;
#pragma unroll
        for (int i = 0; i < 4; ++i) pk[i] = (bf16_t)(acc[m][n][i] + bv);
        const size_t didx =
            ((((size_t)(rrow0 >> 11)) * 16 + (col2 >> 6)) * 64 + (col2 & 63)) * 2048 +
            (rrow0 & 2047);
        *(bf16x4*)&((bf16_t*)out2)[didx] = pk;
      } else {
#pragma unroll
        for (int i = 0; i < 4; ++i) {
          const int rrow = rrow0 + i;
          float v = acc[m][n][i] + bv;
          if (EPI == 1) {
            const size_t idx = (size_t)rrow * N + col;
            v += resid[idx];
            ((float*)out)[idx] = v;
          } else if (EPI == 2) {
            v = 0.5f * v * (1.0f + erff(v * 0.70710678118f));
            ((bf16_t*)out)[(size_t)rrow * N + col] = (bf16_t)v;
          } else if (EPI == 3) {
            ((bf16_t*)out)[(size_t)rrow * 2048 + col] = (bf16_t)v;
          } else {
            ((bf16_t*)out)[(size_t)rrow * N + col] = (bf16_t)v;
          }
        }
      }
    }
}

// ---------------- flash attention v6 ----------------
// r7's winning structure (single-buffer 25.6KB LDS, ~6 blocks/CU, no setprio,
// pad-72 P) + log2-domain online softmax with NATIVE exp2
// (__builtin_amdgcn_exp2f -> v_exp_f32) + defer-max (T13).
// qk: bf16 [8192][2048] (q col 0, k col 1024); vt: bf16 [64bh][64d][2048s]
__global__ __launch_bounds__(256) void flash_attn6(const bf16_t* __restrict__ qk,
                                                   const bf16_t* __restrict__ vt,
                                                   bf16_t* __restrict__ O) {
  const int S = 2048;
  const int qt = blockIdx.x;   // 32 q-tiles of 64 rows
  const int bh = blockIdx.y;   // 64 (b,h)
  const int h = bh & 15;
  const size_t rowbase = (size_t)(bh >> 4) * S;
  const int tid = threadIdx.x, lane = tid & 63, wave = tid >> 6;
  const int g = lane >> 4, lr = lane & 15;
  const int q0w = qt * 64 + wave * 16;
  const float c2 = 0.18033688f;  // 0.125 * log2(e)

  __shared__ __align__(16) bf16_t sK[64 * 64];    // [kv][d], XOR-swizzled chunks
  __shared__ __align__(16) bf16_t sVT[64 * 64];   // [d][kv], XOR-swizzled chunks
  __shared__ __align__(16) bf16_t sP[4][16 * 72]; // per-wave P[q][kv], pad 72

  const bf16_t* vtb = vt + (size_t)bh * 64 * 2048;

  // Q fragments: lane (g,lr) holds Q[q=lr][k=8g+j (+32*st)]
  s16x8 aq[2];
  {
    const bf16_t* qrow = qk + (rowbase + q0w + lr) * 2048 + h * 64;
    aq[0] = *(const s16x8*)(qrow + g * 8);
    aq[1] = *(const s16x8*)(qrow + 32 + g * 8);
  }

  f32x4 oa[4] = {};               // O^T[d=f2*16+4g+i][q=lr]
  float m2 = -1e30f, lrun = 0.0f; // running max (log2-domain), denom

  for (int kv0 = 0; kv0 < S; kv0 += 64) {
    __syncthreads();
    // stage K [64 kv][64 d] and VT [64 d][64 kv]; swizzled source, linear dest
#pragma unroll
    for (int p = 0; p < 2; ++p) {
      const int c = p * 256 + wave * 64 + lane;
      const int r = c >> 3;
      const int pb = (c & 7) ^ (r & 7);
      char* dK = (char*)sK + (size_t)(p * 256 + wave * 64) * 16;
      char* dV = (char*)sVT + (size_t)(p * 256 + wave * 64) * 16;
      gload_lds16(qk + (rowbase + kv0 + r) * 2048 + 1024 + h * 64 + pb * 8, dK);
      gload_lds16(vtb + (size_t)r * 2048 + kv0 + pb * 8, dV);
    }
    __syncthreads();

    // swapped QK^T: lane holds S[q=lr][kv=fr*16+4g+i] (raw scores)
    f32x4 sc[4] = {};
#pragma unroll
    for (int st = 0; st < 2; ++st)
#pragma unroll
      for (int fr = 0; fr < 4; ++fr) {
        const int pb = (g + 4 * st) ^ (lr & 7);
        const s16x8 ak = *(const s16x8*)&sK[(fr * 16 + lr) * 64 + pb * 8];
        sc[fr] = mfma16(ak, aq[st], sc[fr]);
      }

    // online softmax in log2-domain with defer-max (T13), native exp2
    float rmax = fmaxf(fmaxf(sc[0][0], sc[0][1]), fmaxf(sc[0][2], sc[0][3]));
#pragma unroll
    for (int fr = 1; fr < 4; ++fr)
#pragma unroll
      for (int i = 0; i < 4; ++i) rmax = fmaxf(rmax, sc[fr][i]);
    rmax = fmaxf(rmax, __shfl_xor(rmax, 16));
    rmax = fmaxf(rmax, __shfl_xor(rmax, 32));
    const float pm2 = rmax * c2;
    if (!__all(pm2 <= m2 + 8.0f)) {
      const float mn = fmaxf(m2, pm2);
      const float alpha = fexp2(m2 - mn);
      m2 = mn;
      lrun *= alpha;
#pragma unroll
      for (int f2 = 0; f2 < 4; ++f2)
#pragma unroll
        for (int i = 0; i < 4; ++i) oa[f2][i] *= alpha;
    }
    float rsum = 0.0f;
#pragma unroll
    for (int fr = 0; fr < 4; ++fr)
#pragma unroll
      for (int i = 0; i < 4; ++i) {
        const float pp = fexp2(fmaf(sc[fr][i], c2, -m2));
        sc[fr][i] = pp;
        rsum += pp;
      }
    rsum += __shfl_xor(rsum, 16);
    rsum += __shfl_xor(rsum, 32);
    lrun += rsum;

    // P[q=lr][kv]: in-lane kv-contiguous -> vectorized b64 writes (per-wave LDS)
#pragma unroll
    for (int fr = 0; fr < 4; ++fr) {
      bf16x4 pk;
#pragma unroll
      for (int i = 0; i < 4; ++i) pk[i] = (bf16_t)sc[fr][i];
      *(bf16x4*)&sP[wave][lr * 72 + fr * 16 + 4 * g] = pk;
    }

    // PV: O^T += mfma(VT-frag, P-frag)  (same-wave LDS, in-order, no barrier)
#pragma unroll
    for (int st = 0; st < 2; ++st) {
      const s16x8 pa = *(const s16x8*)&sP[wave][lr * 72 + st * 32 + g * 8];
#pragma unroll
      for (int f2 = 0; f2 < 4; ++f2) {
        const int pb = (g + 4 * st) ^ (lr & 7);
        const s16x8 va = *(const s16x8*)&sVT[(f2 * 16 + lr) * 64 + pb * 8];
        oa[f2] = mfma16(va, pa, oa[f2]);
      }
    }
  }

  const float rl = 1.0f / lrun;
#pragma unroll
  for (int f2 = 0; f2 < 4; ++f2) {
    bf16x4 ov;
#pragma unroll
    for (int i = 0; i < 4; ++i) ov[i] = (bf16_t)(oa[f2][i] * rl);
    *(bf16x4*)&O[(rowbase + q0w + lr) * 1024 + h * 64 + f2 * 16 + 4 * g] = ov;
  }
}

// ---------------- launch ----------------
extern "C" void kernel_launch(void* const* d_in, const int* in_sizes, int n_in,
                              void* d_out, int out_size, void* d_ws, size_t ws_size,
                              hipStream_t stream) {
  const float* x    = (const float*)d_in[0];
  const float* ln1w = (const float*)d_in[1];
  const float* ln1b = (const float*)d_in[2];
  const float* Wqkv = (const float*)d_in[3];
  const float* bqkv = (const float*)d_in[4];
  const float* Wo   = (const float*)d_in[5];
  const float* bo   = (const float*)d_in[6];
  const float* ln2w = (const float*)d_in[7];
  const float* ln2b = (const float*)d_in[8];
  const float* fc1w = (const float*)d_in[9];
  const float* fc1b = (const float*)d_in[10];
  const float* fc2w = (const float*)d_in[11];
  const float* fc2b = (const float*)d_in[12];

  const int M = 8192;

  char* ws = (char*)d_ws;
  size_t off = 0;
  auto alloc = [&](size_t bytes) {
    char* p = ws + off;
    off += (bytes + 255) & ~(size_t)255;
    return p;
  };
  // persistent weights (bf16, transposed)
  bf16_t* WqkvT = (bf16_t*)alloc((size_t)3072 * 1024 * 2);   // 6 MB
  bf16_t* WoT   = (bf16_t*)alloc((size_t)1024 * 1024 * 2);   // 2 MB
  bf16_t* fc1T  = (bf16_t*)alloc((size_t)4096 * 1024 * 2);   // 8 MB
  bf16_t* fc2T  = (bf16_t*)alloc((size_t)1024 * 4096 * 2);   // 8 MB
  // activations
  bf16_t* h1    = (bf16_t*)alloc((size_t)M * 1024 * 2);      // 16 MB (reused as h2)
  bf16_t* qkQK  = (bf16_t*)alloc((size_t)M * 2048 * 2);      // 32 MB (attn region pt 1)
  bf16_t* vTg   = (bf16_t*)alloc((size_t)M * 1024 * 2);      // 16 MB (pt 2)
  bf16_t* attnO = (bf16_t*)alloc((size_t)M * 1024 * 2);      // 16 MB (pt 3)
  float*  x2    = (float*)alloc((size_t)M * 1024 * 4);       // 32 MB
  // aliases: lifetimes disjoint in stream order
  bf16_t* h2   = h1;     // h1 dead after QKV GEMM
  bf16_t* gbuf = qkQK;   // qkQK/vTg dead after attn, attnO dead after o-proj
  if (off > ws_size) return;  // ~136 MB required

  const dim3 tb(32, 8);
  tcast_kernel<<<dim3(96, 32), tb, 0, stream>>>(Wqkv, WqkvT, 1024, 3072);
  tcast_kernel<<<dim3(32, 32), tb, 0, stream>>>(Wo, WoT, 1024, 1024);
  tcast_kernel<<<dim3(128, 32), tb, 0, stream>>>(fc1w, fc1T, 1024, 4096);
  tcast_kernel<<<dim3(32, 128), tb, 0, stream>>>(fc2w, fc2T, 4096, 1024);

  ln_kernel<<<M, 256, 0, stream>>>(x, ln1w, ln1b, h1);

  gemm128b<3><<<dim3(1536), 256, 0, stream>>>(h1, WqkvT, bqkv, nullptr, qkQK, vTg, M, 3072, 1024);

  flash_attn6<<<dim3(32, 64), 256, 0, stream>>>(qkQK, vTg, attnO);

  gemm128b<1><<<dim3(512), 256, 0, stream>>>(attnO, WoT, bo, x, x2, nullptr, M, 1024, 1024);

  ln_kernel<<<M, 256, 0, stream>>>(x2, ln2w, ln2b, h2);

  gemm128b<2><<<dim3(2048), 256, 0, stream>>>(h2, fc1T, fc1b, nullptr, gbuf, nullptr, M, 4096, 1024);

  gemm128b<1><<<dim3(512), 256, 0, stream>>>(gbuf, fc2T, fc2b, x2, (float*)d_out, nullptr, M, 1024, 4096);
}

// Round 12
// 438.408 us; speedup vs baseline: 1.0757x; 1.0041x over previous
//
#include <hip/hip_runtime.h>
#include <hip/hip_bf16.h>
#include <math.h>

typedef __bf16 bf16_t;
typedef __bf16 bf16x4 __attribute__((ext_vector_type(4)));
typedef short  s16x8  __attribute__((ext_vector_type(8)));
typedef float  f32x4  __attribute__((ext_vector_type(4)));

#define DEVINL __device__ __forceinline__

DEVINL void gload_lds16(const void* g, void* l) {
  __builtin_amdgcn_global_load_lds(
      (const __attribute__((address_space(1))) unsigned int*)g,
      (__attribute__((address_space(3))) unsigned int*)l, 16, 0, 0);
}

DEVINL f32x4 mfma16(s16x8 a, s16x8 b, f32x4 c) {
  return __builtin_amdgcn_mfma_f32_16x16x32_bf16(a, b, c, 0, 0, 0);
}

DEVINL float fexp2(float x) { return __builtin_amdgcn_exp2f(x); }  // native v_exp_f32

// ---------------- transpose + cast: W[K][N] f32 -> WT[N][K] bf16 ----------------
__global__ __launch_bounds__(256) void tcast_kernel(const float* __restrict__ W,
                                                    bf16_t* __restrict__ WT,
                                                    int K, int N) {
  __shared__ float tile[32][33];
  const int n0 = blockIdx.x * 32, k0 = blockIdx.y * 32;
  const int tx = threadIdx.x, ty = threadIdx.y;
#pragma unroll
  for (int j = 0; j < 4; ++j)
    tile[ty + j * 8][tx] = W[(size_t)(k0 + ty + j * 8) * N + (n0 + tx)];
  __syncthreads();
#pragma unroll
  for (int j = 0; j < 4; ++j)
    WT[(size_t)(n0 + ty + j * 8) * K + (k0 + tx)] = (bf16_t)tile[tx][ty + j * 8];
}

// ---------------- layernorm: f32 [rows][1024] -> bf16 ----------------
__global__ __launch_bounds__(256) void ln_kernel(const float* __restrict__ x,
                                                 const float* __restrict__ w,
                                                 const float* __restrict__ b,
                                                 bf16_t* __restrict__ out) {
  const int row = blockIdx.x, tid = threadIdx.x;
  const float4 v = ((const float4*)(x + (size_t)row * 1024))[tid];
  float s  = v.x + v.y + v.z + v.w;
  float s2 = v.x * v.x + v.y * v.y + v.z * v.z + v.w * v.w;
#pragma unroll
  for (int off = 32; off > 0; off >>= 1) {
    s  += __shfl_down(s, off);
    s2 += __shfl_down(s2, off);
  }
  __shared__ float red[8];
  const int wave = tid >> 6, lane = tid & 63;
  if (lane == 0) { red[wave] = s; red[4 + wave] = s2; }
  __syncthreads();
  s  = red[0] + red[1] + red[2] + red[3];
  s2 = red[4] + red[5] + red[6] + red[7];
  const float mu = s * (1.0f / 1024.0f);
  const float rs = rsqrtf(s2 * (1.0f / 1024.0f) - mu * mu + 1e-5f);
  const float4 wv = ((const float4*)w)[tid];
  const float4 bv = ((const float4*)b)[tid];
  bf16x4 o;
  o[0] = (bf16_t)((v.x - mu) * rs * wv.x + bv.x);
  o[1] = (bf16_t)((v.y - mu) * rs * wv.y + bv.y);
  o[2] = (bf16_t)((v.z - mu) * rs * wv.z + bv.z);
  o[3] = (bf16_t)((v.w - mu) * rs * wv.w + bv.w);
  ((bf16x4*)(out + (size_t)row * 1024))[tid] = o;
}

// ---------------- 128x128 GEMM, BK=64, TLP-based (m97 family) ----------------
// EPI 0: +bias -> bf16 | 1: +bias+resid -> f32 | 2: gelu -> bf16 | 3: qkv split
template <int EPI>
__global__ __launch_bounds__(256, 4) void gemm128b(const bf16_t* __restrict__ A,
                                                   const bf16_t* __restrict__ BT,
                                                   const float* __restrict__ bias,
                                                   const float* __restrict__ resid,
                                                   void* __restrict__ out,
                                                   void* __restrict__ out2,
                                                   int M, int N, int K) {
  __shared__ __align__(16) bf16_t sA[128 * 64];
  __shared__ __align__(16) bf16_t sB[128 * 64];
  const int tid = threadIdx.x;
  const int lane = tid & 63, wave = tid >> 6;
  const int wr = wave >> 1, wc = wave & 1;
  const int g = lane >> 4, lr = lane & 15;

  const int bid = blockIdx.x;
  const int cpx = gridDim.x >> 3;
  const int gid = (bid & 7) * cpx + (bid >> 3);
  const int m0 = (gid & 63) * 128, n0 = (gid >> 6) * 128;
  const bf16_t* Ab = A + (size_t)m0 * K;
  const bf16_t* Bb = BT + (size_t)n0 * K;

  f32x4 acc[4][4] = {};

  for (int kt = 0; kt < K; kt += 64) {
    __syncthreads();
#pragma unroll
    for (int q = 0; q < 4; ++q) {
      const int c = q * 256 + tid;
      const int r = c >> 3;
      const int j = (c & 7) ^ (r & 7);
      const size_t doff = (size_t)(q * 256 + wave * 64) * 8;
      gload_lds16(Ab + (size_t)r * K + kt + j * 8, sA + doff);
      gload_lds16(Bb + (size_t)r * K + kt + j * 8, sB + doff);
    }
    __syncthreads();
#pragma unroll
    for (int ks = 0; ks < 2; ++ks) {
      s16x8 af[4], bfr[4];
#pragma unroll
      for (int m = 0; m < 4; ++m) {
        const int r = wr * 64 + m * 16 + lr;
        af[m] = *(const s16x8*)&sA[r * 64 + (((ks << 2) + g) ^ (r & 7)) * 8];
      }
#pragma unroll
      for (int n = 0; n < 4; ++n) {
        const int r = wc * 64 + n * 16 + lr;
        bfr[n] = *(const s16x8*)&sB[r * 64 + (((ks << 2) + g) ^ (r & 7)) * 8];
      }
#pragma unroll
      for (int m = 0; m < 4; ++m)
#pragma unroll
        for (int n = 0; n < 4; ++n)
          acc[m][n] = mfma16(af[m], bfr[n], acc[m][n]);
    }
  }

#pragma unroll
  for (int m = 0; m < 4; ++m)
#pragma unroll
    for (int n = 0; n < 4; ++n) {
      const int col = n0 + wc * 64 + n * 16 + lr;
      const float bv = bias[col];
      const int rrow0 = m0 + wr * 64 + m * 16 + g * 4;
      if (EPI == 3 && col >= 2048) {
        const int col2 = col - 2048;
        bf16x4 pk;
#pragma unroll
        for (int i = 0; i < 4; ++i) pk[i] = (bf16_t)(acc[m][n][i] + bv);
        const size_t didx =
            ((((size_t)(rrow0 >> 11)) * 16 + (col2 >> 6)) * 64 + (col2 & 63)) * 2048 +
            (rrow0 & 2047);
        *(bf16x4*)&((bf16_t*)out2)[didx] = pk;
      } else {
#pragma unroll
        for (int i = 0; i < 4; ++i) {
          const int rrow = rrow0 + i;
          float v = acc[m][n][i] + bv;
          if (EPI == 1) {
            const size_t idx = (size_t)rrow * N + col;
            v += resid[idx];
            ((float*)out)[idx] = v;
          } else if (EPI == 2) {
            v = 0.5f * v * (1.0f + erff(v * 0.70710678118f));
            ((bf16_t*)out)[(size_t)rrow * N + col] = (bf16_t)v;
          } else if (EPI == 3) {
            ((bf16_t*)out)[(size_t)rrow * 2048 + col] = (bf16_t)v;
          } else {
            ((bf16_t*)out)[(size_t)rrow * N + col] = (bf16_t)v;
          }
        }
      }
    }
}

// ---------------- flash attention v7 ----------------
// = v6 (r11 winner: single-buffer LDS, log2-domain softmax w/ native exp2,
// defer-max, pad-72 P) + XCD-chunked 1D grid (T1): each XCD owns 8 bh's all
// q-tiles -> its K/V working set (8 x 512 KB = 4 MB) fits its private L2.
// qk: bf16 [8192][2048] (q col 0, k col 1024); vt: bf16 [64bh][64d][2048s]
__global__ __launch_bounds__(256) void flash_attn7(const bf16_t* __restrict__ qk,
                                                   const bf16_t* __restrict__ vt,
                                                   bf16_t* __restrict__ O) {
  const int S = 2048;
  // chunked XCD swizzle: 2048 blocks, 256 per XCD chunk; bh-major within chunk
  const int bid = blockIdx.x;
  const int swz = (bid & 7) * 256 + (bid >> 3);
  const int bh = swz >> 5;     // 64 (b,h)
  const int qt = swz & 31;     // 32 q-tiles of 64 rows
  const int h = bh & 15;
  const size_t rowbase = (size_t)(bh >> 4) * S;
  const int tid = threadIdx.x, lane = tid & 63, wave = tid >> 6;
  const int g = lane >> 4, lr = lane & 15;
  const int q0w = qt * 64 + wave * 16;
  const float c2 = 0.18033688f;  // 0.125 * log2(e)

  __shared__ __align__(16) bf16_t sK[64 * 64];    // [kv][d], XOR-swizzled chunks
  __shared__ __align__(16) bf16_t sVT[64 * 64];   // [d][kv], XOR-swizzled chunks
  __shared__ __align__(16) bf16_t sP[4][16 * 72]; // per-wave P[q][kv], pad 72

  const bf16_t* vtb = vt + (size_t)bh * 64 * 2048;

  // Q fragments: lane (g,lr) holds Q[q=lr][k=8g+j (+32*st)]
  s16x8 aq[2];
  {
    const bf16_t* qrow = qk + (rowbase + q0w + lr) * 2048 + h * 64;
    aq[0] = *(const s16x8*)(qrow + g * 8);
    aq[1] = *(const s16x8*)(qrow + 32 + g * 8);
  }

  f32x4 oa[4] = {};               // O^T[d=f2*16+4g+i][q=lr]
  float m2 = -1e30f, lrun = 0.0f; // running max (log2-domain), denom

  for (int kv0 = 0; kv0 < S; kv0 += 64) {
    __syncthreads();
    // stage K [64 kv][64 d] and VT [64 d][64 kv]; swizzled source, linear dest
#pragma unroll
    for (int p = 0; p < 2; ++p) {
      const int c = p * 256 + wave * 64 + lane;
      const int r = c >> 3;
      const int pb = (c & 7) ^ (r & 7);
      char* dK = (char*)sK + (size_t)(p * 256 + wave * 64) * 16;
      char* dV = (char*)sVT + (size_t)(p * 256 + wave * 64) * 16;
      gload_lds16(qk + (rowbase + kv0 + r) * 2048 + 1024 + h * 64 + pb * 8, dK);
      gload_lds16(vtb + (size_t)r * 2048 + kv0 + pb * 8, dV);
    }
    __syncthreads();

    // swapped QK^T: lane holds S[q=lr][kv=fr*16+4g+i] (raw scores)
    f32x4 sc[4] = {};
#pragma unroll
    for (int st = 0; st < 2; ++st)
#pragma unroll
      for (int fr = 0; fr < 4; ++fr) {
        const int pb = (g + 4 * st) ^ (lr & 7);
        const s16x8 ak = *(const s16x8*)&sK[(fr * 16 + lr) * 64 + pb * 8];
        sc[fr] = mfma16(ak, aq[st], sc[fr]);
      }

    // online softmax in log2-domain with defer-max (T13), native exp2
    float rmax = fmaxf(fmaxf(sc[0][0], sc[0][1]), fmaxf(sc[0][2], sc[0][3]));
#pragma unroll
    for (int fr = 1; fr < 4; ++fr)
#pragma unroll
      for (int i = 0; i < 4; ++i) rmax = fmaxf(rmax, sc[fr][i]);
    rmax = fmaxf(rmax, __shfl_xor(rmax, 16));
    rmax = fmaxf(rmax, __shfl_xor(rmax, 32));
    const float pm2 = rmax * c2;
    if (!__all(pm2 <= m2 + 8.0f)) {
      const float mn = fmaxf(m2, pm2);
      const float alpha = fexp2(m2 - mn);
      m2 = mn;
      lrun *= alpha;
#pragma unroll
      for (int f2 = 0; f2 < 4; ++f2)
#pragma unroll
        for (int i = 0; i < 4; ++i) oa[f2][i] *= alpha;
    }
    float rsum = 0.0f;
#pragma unroll
    for (int fr = 0; fr < 4; ++fr)
#pragma unroll
      for (int i = 0; i < 4; ++i) {
        const float pp = fexp2(fmaf(sc[fr][i], c2, -m2));
        sc[fr][i] = pp;
        rsum += pp;
      }
    rsum += __shfl_xor(rsum, 16);
    rsum += __shfl_xor(rsum, 32);
    lrun += rsum;

    // P[q=lr][kv]: in-lane kv-contiguous -> vectorized b64 writes (per-wave LDS)
#pragma unroll
    for (int fr = 0; fr < 4; ++fr) {
      bf16x4 pk;
#pragma unroll
      for (int i = 0; i < 4; ++i) pk[i] = (bf16_t)sc[fr][i];
      *(bf16x4*)&sP[wave][lr * 72 + fr * 16 + 4 * g] = pk;
    }

    // PV: O^T += mfma(VT-frag, P-frag)  (same-wave LDS, in-order, no barrier)
#pragma unroll
    for (int st = 0; st < 2; ++st) {
      const s16x8 pa = *(const s16x8*)&sP[wave][lr * 72 + st * 32 + g * 8];
#pragma unroll
      for (int f2 = 0; f2 < 4; ++f2) {
        const int pb = (g + 4 * st) ^ (lr & 7);
        const s16x8 va = *(const s16x8*)&sVT[(f2 * 16 + lr) * 64 + pb * 8];
        oa[f2] = mfma16(va, pa, oa[f2]);
      }
    }
  }

  const float rl = 1.0f / lrun;
#pragma unroll
  for (int f2 = 0; f2 < 4; ++f2) {
    bf16x4 ov;
#pragma unroll
    for (int i = 0; i < 4; ++i) ov[i] = (bf16_t)(oa[f2][i] * rl);
    *(bf16x4*)&O[(rowbase + q0w + lr) * 1024 + h * 64 + f2 * 16 + 4 * g] = ov;
  }
}

// ---------------- launch ----------------
extern "C" void kernel_launch(void* const* d_in, const int* in_sizes, int n_in,
                              void* d_out, int out_size, void* d_ws, size_t ws_size,
                              hipStream_t stream) {
  const float* x    = (const float*)d_in[0];
  const float* ln1w = (const float*)d_in[1];
  const float* ln1b = (const float*)d_in[2];
  const float* Wqkv = (const float*)d_in[3];
  const float* bqkv = (const float*)d_in[4];
  const float* Wo   = (const float*)d_in[5];
  const float* bo   = (const float*)d_in[6];
  const float* ln2w = (const float*)d_in[7];
  const float* ln2b = (const float*)d_in[8];
  const float* fc1w = (const float*)d_in[9];
  const float* fc1b = (const float*)d_in[10];
  const float* fc2w = (const float*)d_in[11];
  const float* fc2b = (const float*)d_in[12];

  const int M = 8192;

  char* ws = (char*)d_ws;
  size_t off = 0;
  auto alloc = [&](size_t bytes) {
    char* p = ws + off;
    off += (bytes + 255) & ~(size_t)255;
    return p;
  };
  // persistent weights (bf16, transposed)
  bf16_t* WqkvT = (bf16_t*)alloc((size_t)3072 * 1024 * 2);   // 6 MB
  bf16_t* WoT   = (bf16_t*)alloc((size_t)1024 * 1024 * 2);   // 2 MB
  bf16_t* fc1T  = (bf16_t*)alloc((size_t)4096 * 1024 * 2);   // 8 MB
  bf16_t* fc2T  = (bf16_t*)alloc((size_t)1024 * 4096 * 2);   // 8 MB
  // activations
  bf16_t* h1    = (bf16_t*)alloc((size_t)M * 1024 * 2);      // 16 MB (reused as h2)
  bf16_t* qkQK  = (bf16_t*)alloc((size_t)M * 2048 * 2);      // 32 MB (attn region pt 1)
  bf16_t* vTg   = (bf16_t*)alloc((size_t)M * 1024 * 2);      // 16 MB (pt 2)
  bf16_t* attnO = (bf16_t*)alloc((size_t)M * 1024 * 2);      // 16 MB (pt 3)
  float*  x2    = (float*)alloc((size_t)M * 1024 * 4);       // 32 MB
  // aliases: lifetimes disjoint in stream order
  bf16_t* h2   = h1;     // h1 dead after QKV GEMM
  bf16_t* gbuf = qkQK;   // qkQK/vTg dead after attn, attnO dead after o-proj
  if (off > ws_size) return;  // ~136 MB required

  const dim3 tb(32, 8);
  tcast_kernel<<<dim3(96, 32), tb, 0, stream>>>(Wqkv, WqkvT, 1024, 3072);
  tcast_kernel<<<dim3(32, 32), tb, 0, stream>>>(Wo, WoT, 1024, 1024);
  tcast_kernel<<<dim3(128, 32), tb, 0, stream>>>(fc1w, fc1T, 1024, 4096);
  tcast_kernel<<<dim3(32, 128), tb, 0, stream>>>(fc2w, fc2T, 4096, 1024);

  ln_kernel<<<M, 256, 0, stream>>>(x, ln1w, ln1b, h1);

  gemm128b<3><<<dim3(1536), 256, 0, stream>>>(h1, WqkvT, bqkv, nullptr, qkQK, vTg, M, 3072, 1024);

  flash_attn7<<<dim3(2048), 256, 0, stream>>>(qkQK, vTg, attnO);

  gemm128b<1><<<dim3(512), 256, 0, stream>>>(attnO, WoT, bo, x, x2, nullptr, M, 1024, 1024);

  ln_kernel<<<M, 256, 0, stream>>>(x2, ln2w, ln2b, h2);

  gemm128b<2><<<dim3(2048), 256, 0, stream>>>(h2, fc1T, fc1b, nullptr, gbuf, nullptr, M, 4096, 1024);

  gemm128b<1><<<dim3(512), 256, 0, stream>>>(gbuf, fc2T, fc2b, x2, (float*)d_out, nullptr, M, 1024, 4096);
}

// Round 13
// 433.259 us; speedup vs baseline: 1.0885x; 1.0119x over previous
//
#include <hip/hip_runtime.h>
#include <hip/hip_bf16.h>
#include <math.h>

typedef __bf16 bf16_t;
typedef __bf16 bf16x4 __attribute__((ext_vector_type(4)));
typedef short  s16x8  __attribute__((ext_vector_type(8)));
typedef float  f32x4  __attribute__((ext_vector_type(4)));
typedef float  f32x16 __attribute__((ext_vector_type(16)));

#define DEVINL __device__ __forceinline__

DEVINL void gload_lds16(const void* g, void* l) {
  __builtin_amdgcn_global_load_lds(
      (const __attribute__((address_space(1))) unsigned int*)g,
      (__attribute__((address_space(3))) unsigned int*)l, 16, 0, 0);
}

DEVINL f32x4 mfma16(s16x8 a, s16x8 b, f32x4 c) {
  return __builtin_amdgcn_mfma_f32_16x16x32_bf16(a, b, c, 0, 0, 0);
}

DEVINL f32x16 mfma32(s16x8 a, s16x8 b, f32x16 c) {
  return __builtin_amdgcn_mfma_f32_32x32x16_bf16(a, b, c, 0, 0, 0);
}

DEVINL float fexp2(float x) { return __builtin_amdgcn_exp2f(x); }  // native v_exp_f32

// ---------------- transpose + cast: W[K][N] f32 -> WT[N][K] bf16 ----------------
__global__ __launch_bounds__(256) void tcast_kernel(const float* __restrict__ W,
                                                    bf16_t* __restrict__ WT,
                                                    int K, int N) {
  __shared__ float tile[32][33];
  const int n0 = blockIdx.x * 32, k0 = blockIdx.y * 32;
  const int tx = threadIdx.x, ty = threadIdx.y;
#pragma unroll
  for (int j = 0; j < 4; ++j)
    tile[ty + j * 8][tx] = W[(size_t)(k0 + ty + j * 8) * N + (n0 + tx)];
  __syncthreads();
#pragma unroll
  for (int j = 0; j < 4; ++j)
    WT[(size_t)(n0 + ty + j * 8) * K + (k0 + tx)] = (bf16_t)tile[tx][ty + j * 8];
}

// ---------------- layernorm: f32 [rows][1024] -> bf16 ----------------
__global__ __launch_bounds__(256) void ln_kernel(const float* __restrict__ x,
                                                 const float* __restrict__ w,
                                                 const float* __restrict__ b,
                                                 bf16_t* __restrict__ out) {
  const int row = blockIdx.x, tid = threadIdx.x;
  const float4 v = ((const float4*)(x + (size_t)row * 1024))[tid];
  float s  = v.x + v.y + v.z + v.w;
  float s2 = v.x * v.x + v.y * v.y + v.z * v.z + v.w * v.w;
#pragma unroll
  for (int off = 32; off > 0; off >>= 1) {
    s  += __shfl_down(s, off);
    s2 += __shfl_down(s2, off);
  }
  __shared__ float red[8];
  const int wave = tid >> 6, lane = tid & 63;
  if (lane == 0) { red[wave] = s; red[4 + wave] = s2; }
  __syncthreads();
  s  = red[0] + red[1] + red[2] + red[3];
  s2 = red[4] + red[5] + red[6] + red[7];
  const float mu = s * (1.0f / 1024.0f);
  const float rs = rsqrtf(s2 * (1.0f / 1024.0f) - mu * mu + 1e-5f);
  const float4 wv = ((const float4*)w)[tid];
  const float4 bv = ((const float4*)b)[tid];
  bf16x4 o;
  o[0] = (bf16_t)((v.x - mu) * rs * wv.x + bv.x);
  o[1] = (bf16_t)((v.y - mu) * rs * wv.y + bv.y);
  o[2] = (bf16_t)((v.z - mu) * rs * wv.z + bv.z);
  o[3] = (bf16_t)((v.w - mu) * rs * wv.w + bv.w);
  ((bf16x4*)(out + (size_t)row * 1024))[tid] = o;
}

// ---------------- 128x128 GEMM, BK=64, TLP-based (m97 family) ----------------
// EPI 0: +bias -> bf16 | 1: +bias+resid -> f32 | 2: gelu -> bf16 | 3: qkv split
template <int EPI>
__global__ __launch_bounds__(256, 4) void gemm128b(const bf16_t* __restrict__ A,
                                                   const bf16_t* __restrict__ BT,
                                                   const float* __restrict__ bias,
                                                   const float* __restrict__ resid,
                                                   void* __restrict__ out,
                                                   void* __restrict__ out2,
                                                   int M, int N, int K) {
  __shared__ __align__(16) bf16_t sA[128 * 64];
  __shared__ __align__(16) bf16_t sB[128 * 64];
  const int tid = threadIdx.x;
  const int lane = tid & 63, wave = tid >> 6;
  const int wr = wave >> 1, wc = wave & 1;
  const int g = lane >> 4, lr = lane & 15;

  const int bid = blockIdx.x;
  const int cpx = gridDim.x >> 3;
  const int gid = (bid & 7) * cpx + (bid >> 3);
  const int m0 = (gid & 63) * 128, n0 = (gid >> 6) * 128;
  const bf16_t* Ab = A + (size_t)m0 * K;
  const bf16_t* Bb = BT + (size_t)n0 * K;

  f32x4 acc[4][4] = {};

  for (int kt = 0; kt < K; kt += 64) {
    __syncthreads();
#pragma unroll
    for (int q = 0; q < 4; ++q) {
      const int c = q * 256 + tid;
      const int r = c >> 3;
      const int j = (c & 7) ^ (r & 7);
      const size_t doff = (size_t)(q * 256 + wave * 64) * 8;
      gload_lds16(Ab + (size_t)r * K + kt + j * 8, sA + doff);
      gload_lds16(Bb + (size_t)r * K + kt + j * 8, sB + doff);
    }
    __syncthreads();
#pragma unroll
    for (int ks = 0; ks < 2; ++ks) {
      s16x8 af[4], bfr[4];
#pragma unroll
      for (int m = 0; m < 4; ++m) {
        const int r = wr * 64 + m * 16 + lr;
        af[m] = *(const s16x8*)&sA[r * 64 + (((ks << 2) + g) ^ (r & 7)) * 8];
      }
#pragma unroll
      for (int n = 0; n < 4; ++n) {
        const int r = wc * 64 + n * 16 + lr;
        bfr[n] = *(const s16x8*)&sB[r * 64 + (((ks << 2) + g) ^ (r & 7)) * 8];
      }
#pragma unroll
      for (int m = 0; m < 4; ++m)
#pragma unroll
        for (int n = 0; n < 4; ++n)
          acc[m][n] = mfma16(af[m], bfr[n], acc[m][n]);
    }
  }

#pragma unroll
  for (int m = 0; m < 4; ++m)
#pragma unroll
    for (int n = 0; n < 4; ++n) {
      const int col = n0 + wc * 64 + n * 16 + lr;
      const float bv = bias[col];
      const int rrow0 = m0 + wr * 64 + m * 16 + g * 4;
      if (EPI == 3 && col >= 2048) {
        const int col2 = col - 2048;
        bf16x4 pk;
#pragma unroll
        for (int i = 0; i < 4; ++i) pk[i] = (bf16_t)(acc[m][n][i] + bv);
        const size_t didx =
            ((((size_t)(rrow0 >> 11)) * 16 + (col2 >> 6)) * 64 + (col2 & 63)) * 2048 +
            (rrow0 & 2047);
        *(bf16x4*)&((bf16_t*)out2)[didx] = pk;
      } else {
#pragma unroll
        for (int i = 0; i < 4; ++i) {
          const int rrow = rrow0 + i;
          float v = acc[m][n][i] + bv;
          if (EPI == 1) {
            const size_t idx = (size_t)rrow * N + col;
            v += resid[idx];
            ((float*)out)[idx] = v;
          } else if (EPI == 2) {
            v = 0.5f * v * (1.0f + erff(v * 0.70710678118f));
            ((bf16_t*)out)[(size_t)rrow * N + col] = (bf16_t)v;
          } else if (EPI == 3) {
            ((bf16_t*)out)[(size_t)rrow * 2048 + col] = (bf16_t)v;
          } else {
            ((bf16_t*)out)[(size_t)rrow * N + col] = (bf16_t)v;
          }
        }
      }
    }
}

// ---------------- flash attention v8: 32x32x16 MFMA ----------------
// 4 waves x 32 q = 128 q/block; grid 1024 (XCD-chunked). Swapped QK^T at
// 32x32: C layout col=q=lane&31, row=kv=(reg&3)+8(reg>>2)+4H (m74/m101).
// A-frag: row=lane&31, k=8H+j. Softmax: 32 in-lane + 1 shfl_xor(32).
// P via per-wave chunk-rotated [32][64] LDS. Keepers: XOR-swizzled staging,
// log2-domain softmax + native exp2 + defer-max.
__global__ __launch_bounds__(256) void flash_attn8(const bf16_t* __restrict__ qk,
                                                   const bf16_t* __restrict__ vt,
                                                   bf16_t* __restrict__ O) {
  const int S = 2048;
  const int bid = blockIdx.x;                 // 1024 blocks
  const int swz = (bid & 7) * 128 + (bid >> 3);
  const int bh = swz >> 4;                    // 64 (b,h)
  const int qt = swz & 15;                    // 16 q-tiles of 128 rows
  const int h = bh & 15;
  const size_t rowbase = (size_t)(bh >> 4) * S;
  const int tid = threadIdx.x, lane = tid & 63, wave = tid >> 6;
  const int ql = lane & 31;                   // q (and A-row) lane index
  const int H = lane >> 5;                    // lane half
  const int q0w = qt * 128 + wave * 32;
  const float c2 = 0.18033688f;               // 0.125 * log2(e)

  __shared__ __align__(16) bf16_t sK[64 * 64];     // [kv][d], XOR-swizzled chunks
  __shared__ __align__(16) bf16_t sVT[64 * 64];    // [d][kv], XOR-swizzled chunks
  __shared__ __align__(16) bf16_t sP[4][32 * 64];  // per-wave P, chunk-rotated rows

  const bf16_t* vtb = vt + (size_t)bh * 64 * 2048;

  // Q B-frags: frag ks holds Q[q0w+ql][d = 16ks + 8H + j]
  s16x8 qf[4];
  {
    const bf16_t* qrow = qk + (rowbase + q0w + ql) * 2048 + h * 64 + 8 * H;
#pragma unroll
    for (int ks = 0; ks < 4; ++ks) qf[ks] = *(const s16x8*)(qrow + 16 * ks);
  }

  f32x16 oa[2] = {};              // O^T frags: row d = 32df + (r&3)+8(r>>2)+4H, col q=ql
  float m2 = -1e30f, lrun = 0.0f;

  for (int kv0 = 0; kv0 < S; kv0 += 64) {
    __syncthreads();
    // stage K [64 kv][64 d] and VT [64 d][64 kv]; swizzled source, linear dest
#pragma unroll
    for (int p = 0; p < 2; ++p) {
      const int c = p * 256 + wave * 64 + lane;
      const int r = c >> 3;
      const int pb = (c & 7) ^ (r & 7);
      char* dK = (char*)sK + (size_t)(p * 256 + wave * 64) * 16;
      char* dV = (char*)sVT + (size_t)(p * 256 + wave * 64) * 16;
      gload_lds16(qk + (rowbase + kv0 + r) * 2048 + 1024 + h * 64 + pb * 8, dK);
      gload_lds16(vtb + (size_t)r * 2048 + kv0 + pb * 8, dV);
    }
    __syncthreads();

    // swapped QK^T: sc[kvf] = S^T[kv = 32kvf + crow][q = ql]
    f32x16 sc[2] = {};
#pragma unroll
    for (int ks = 0; ks < 4; ++ks)
#pragma unroll
      for (int kvf = 0; kvf < 2; ++kvf) {
        const int R = kvf * 32 + ql;
        const s16x8 ak = *(const s16x8*)&sK[R * 64 + (((2 * ks + H) ^ (R & 7)) * 8)];
        sc[kvf] = mfma32(ak, qf[ks], sc[kvf]);
      }

    // online softmax (log2-domain, defer-max): row q=ql split across lane pair (ql, ql+32)
    float rmax = sc[0][0];
#pragma unroll
    for (int f = 0; f < 2; ++f)
#pragma unroll
      for (int r = 0; r < 16; ++r) rmax = fmaxf(rmax, sc[f][r]);
    rmax = fmaxf(rmax, __shfl_xor(rmax, 32));
    const float pm2 = rmax * c2;
    if (!__all(pm2 <= m2 + 8.0f)) {
      const float mn = fmaxf(m2, pm2);
      const float alpha = fexp2(m2 - mn);
      m2 = mn;
      lrun *= alpha;
#pragma unroll
      for (int f = 0; f < 2; ++f)
#pragma unroll
        for (int r = 0; r < 16; ++r) oa[f][r] *= alpha;
    }
    float rsum = 0.0f;
#pragma unroll
    for (int f = 0; f < 2; ++f)
#pragma unroll
      for (int r = 0; r < 16; ++r) {
        const float pp = fexp2(fmaf(sc[f][r], c2, -m2));
        sc[f][r] = pp;
        rsum += pp;
      }
    rsum += __shfl_xor(rsum, 32);
    lrun += rsum;

    // P[q=ql][kv] -> per-wave LDS, 16B chunks rotated by (chunk+ql)&7.
    // Regs 8(ks&1)+4hi+{0..3} of frag ks>>1 = kv 16ks+8hi+4H+{0..3} (contiguous).
#pragma unroll
    for (int ks = 0; ks < 4; ++ks)
#pragma unroll
      for (int hi = 0; hi < 2; ++hi) {
        const int f = ks >> 1, rb = 8 * (ks & 1) + 4 * hi;
        bf16x4 pk;
#pragma unroll
        for (int e = 0; e < 4; ++e) pk[e] = (bf16_t)sc[f][rb + e];
        const int slot = ((2 * ks + hi) + ql) & 7;
        *(bf16x4*)&sP[wave][ql * 64 + slot * 8 + 4 * H] = pk;
      }

    // PV: O^T += mfma32(VT-frag, P-frag)  (same-wave LDS, in-order)
#pragma unroll
    for (int ks = 0; ks < 4; ++ks) {
      const s16x8 pbf = *(const s16x8*)&sP[wave][ql * 64 + (((2 * ks + H) + ql) & 7) * 8];
#pragma unroll
      for (int df = 0; df < 2; ++df) {
        const int R = df * 32 + ql;
        const s16x8 va = *(const s16x8*)&sVT[R * 64 + (((2 * ks + H) ^ (R & 7)) * 8)];
        oa[df] = mfma32(va, pbf, oa[df]);
      }
    }
  }

  const float rl = 1.0f / lrun;
#pragma unroll
  for (int df = 0; df < 2; ++df)
#pragma unroll
    for (int rr = 0; rr < 4; ++rr) {
      bf16x4 ov;
#pragma unroll
      for (int e = 0; e < 4; ++e) ov[e] = (bf16_t)(oa[df][4 * rr + e] * rl);
      const int d0 = 32 * df + 8 * rr + 4 * H;
      *(bf16x4*)&O[(rowbase + q0w + ql) * 1024 + h * 64 + d0] = ov;
    }
}

// ---------------- launch ----------------
extern "C" void kernel_launch(void* const* d_in, const int* in_sizes, int n_in,
                              void* d_out, int out_size, void* d_ws, size_t ws_size,
                              hipStream_t stream) {
  const float* x    = (const float*)d_in[0];
  const float* ln1w = (const float*)d_in[1];
  const float* ln1b = (const float*)d_in[2];
  const float* Wqkv = (const float*)d_in[3];
  const float* bqkv = (const float*)d_in[4];
  const float* Wo   = (const float*)d_in[5];
  const float* bo   = (const float*)d_in[6];
  const float* ln2w = (const float*)d_in[7];
  const float* ln2b = (const float*)d_in[8];
  const float* fc1w = (const float*)d_in[9];
  const float* fc1b = (const float*)d_in[10];
  const float* fc2w = (const float*)d_in[11];
  const float* fc2b = (const float*)d_in[12];

  const int M = 8192;

  char* ws = (char*)d_ws;
  size_t off = 0;
  auto alloc = [&](size_t bytes) {
    char* p = ws + off;
    off += (bytes + 255) & ~(size_t)255;
    return p;
  };
  // persistent weights (bf16, transposed)
  bf16_t* WqkvT = (bf16_t*)alloc((size_t)3072 * 1024 * 2);   // 6 MB
  bf16_t* WoT   = (bf16_t*)alloc((size_t)1024 * 1024 * 2);   // 2 MB
  bf16_t* fc1T  = (bf16_t*)alloc((size_t)4096 * 1024 * 2);   // 8 MB
  bf16_t* fc2T  = (bf16_t*)alloc((size_t)1024 * 4096 * 2);   // 8 MB
  // activations
  bf16_t* h1    = (bf16_t*)alloc((size_t)M * 1024 * 2);      // 16 MB (reused as h2)
  bf16_t* qkQK  = (bf16_t*)alloc((size_t)M * 2048 * 2);      // 32 MB (attn region pt 1)
  bf16_t* vTg   = (bf16_t*)alloc((size_t)M * 1024 * 2);      // 16 MB (pt 2)
  bf16_t* attnO = (bf16_t*)alloc((size_t)M * 1024 * 2);      // 16 MB (pt 3)
  float*  x2    = (float*)alloc((size_t)M * 1024 * 4);       // 32 MB
  // aliases: lifetimes disjoint in stream order
  bf16_t* h2   = h1;     // h1 dead after QKV GEMM
  bf16_t* gbuf = qkQK;   // qkQK/vTg dead after attn, attnO dead after o-proj
  if (off > ws_size) return;  // ~136 MB required

  const dim3 tb(32, 8);
  tcast_kernel<<<dim3(96, 32), tb, 0, stream>>>(Wqkv, WqkvT, 1024, 3072);
  tcast_kernel<<<dim3(32, 32), tb, 0, stream>>>(Wo, WoT, 1024, 1024);
  tcast_kernel<<<dim3(128, 32), tb, 0, stream>>>(fc1w, fc1T, 1024, 4096);
  tcast_kernel<<<dim3(32, 128), tb, 0, stream>>>(fc2w, fc2T, 4096, 1024);

  ln_kernel<<<M, 256, 0, stream>>>(x, ln1w, ln1b, h1);

  gemm128b<3><<<dim3(1536), 256, 0, stream>>>(h1, WqkvT, bqkv, nullptr, qkQK, vTg, M, 3072, 1024);

  flash_attn8<<<dim3(1024), 256, 0, stream>>>(qkQK, vTg, attnO);

  gemm128b<1><<<dim3(512), 256, 0, stream>>>(attnO, WoT, bo, x, x2, nullptr, M, 1024, 1024);

  ln_kernel<<<M, 256, 0, stream>>>(x2, ln2w, ln2b, h2);

  gemm128b<2><<<dim3(2048), 256, 0, stream>>>(h2, fc1T, fc1b, nullptr, gbuf, nullptr, M, 4096, 1024);

  gemm128b<1><<<dim3(512), 256, 0, stream>>>(gbuf, fc2T, fc2b, x2, (float*)d_out, nullptr, M, 1024, 4096);
}